// Round 12
// baseline (125.511 us; speedup 1.0000x reference)
//
#include <hip/hip_runtime.h>

#define NN 150000
#define NE 600000
#define IND 128
#define HID 64
#define KMAX 32           // CSR bucket stride; in-deg ~Poisson(4), P(>32) ~ 1e-19
#define RANGES 8
#define NPR (NN / RANGES)               // 18750 nodes per range
#define CAP 77824                        // per-range edge capacity (mean 75000, +11 sigma)
#define PARTB ((NE / 4 + 255) / 256)     // 586 partition blocks (4 edges/thread)
#define ZEROB ((NN + 255) / 256)         // 586 zero/convert blocks
#define FILLB2 1024                      // phase-B fill blocks: 128 chunks x 8 ranges
#define CHUNK2 (CAP / 128)               // 608 int2 per phase-B block
#define GEMM_GRID ((NN + 63) / 64)       // 2344

typedef short s16x8 __attribute__((ext_vector_type(8)));
typedef float f32x4 __attribute__((ext_vector_type(4)));

__device__ __forceinline__ unsigned f2bf(float f) {
    unsigned u = __float_as_uint(f);
    return (u + 0x7FFFu + ((u >> 16) & 1u)) >> 16;   // RNE
}

// ---------------- hetero init: edge partition (Phase A) + zero cursor + W->bf16 ----------------
// Partition blocks (0..PARTB-1): scan edge quads once, LDS-histogram by dst range,
// one global reservation atomic per range per block, write compacted (dst,src) pairs.
__global__ __launch_bounds__(256) void k_init(
        const int* __restrict__ rowv, const int* __restrict__ colv,
        int* __restrict__ gcnt, int2* __restrict__ ebuf,
        int* __restrict__ cursor, const float* __restrict__ W1,
        const float* __restrict__ W2, unsigned short* __restrict__ W1b,
        unsigned short* __restrict__ W2b) {
    int tid = threadIdx.x;
    if (blockIdx.x < PARTB) {
        __shared__ int hist[RANGES];
        __shared__ int bases[RANGES];
        if (tid < RANGES) hist[tid] = 0;
        __syncthreads();
        int t = blockIdx.x * 256 + tid;
        bool valid = (t < NE / 4);
        int4 r4, c4;
        int rg[4], sl[4];
        if (valid) {
            r4 = ((const int4*)rowv)[t];
            c4 = ((const int4*)colv)[t];
            rg[0] = c4.x / NPR; sl[0] = atomicAdd(&hist[rg[0]], 1);
            rg[1] = c4.y / NPR; sl[1] = atomicAdd(&hist[rg[1]], 1);
            rg[2] = c4.z / NPR; sl[2] = atomicAdd(&hist[rg[2]], 1);
            rg[3] = c4.w / NPR; sl[3] = atomicAdd(&hist[rg[3]], 1);
        }
        __syncthreads();
        if (tid < RANGES) bases[tid] = atomicAdd(&gcnt[tid], hist[tid]);
        __syncthreads();
        if (valid) {
            int p0 = bases[rg[0]] + sl[0];
            int p1 = bases[rg[1]] + sl[1];
            int p2 = bases[rg[2]] + sl[2];
            int p3 = bases[rg[3]] + sl[3];
            if (p0 < CAP) ebuf[rg[0] * CAP + p0] = make_int2(c4.x, r4.x);
            if (p1 < CAP) ebuf[rg[1] * CAP + p1] = make_int2(c4.y, r4.y);
            if (p2 < CAP) ebuf[rg[2] * CAP + p2] = make_int2(c4.z, r4.z);
            if (p3 < CAP) ebuf[rg[3] * CAP + p3] = make_int2(c4.w, r4.w);
        }
        return;
    }
    int t = (blockIdx.x - PARTB) * 256 + tid;
    if (t < NN) cursor[t] = 0;
    if (t < HID * IND) W1b[t] = (unsigned short)f2bf(W1[t]);
    if (t < HID * HID) W2b[t] = (unsigned short)f2bf(W2[t]);
}

// ---------------- hetero: Phase-B XCD-local CSR fill + gemm1 ----------------
// Fill blocks (b < FILLB2): range = b&7 (round-robin -> one XCD owns a range's
// cursor/csr slice), read the range's COMPACTED edges (L2-resident, no re-read),
// cursor atomic + scatter all XCD-local. Perf-only mapping (G16-safe).
// gemm1: xs[n][c] = bf16( sum_k obs[n][k]*W1[c][k] ) -- UNSCALED (dinv on gather).
// wave = 16 rows x 64 cols; A direct from global; W1 in LDS 16 KB XOR-swizzled.
__global__ __launch_bounds__(256) void k_fill_gemm1(
        const float* __restrict__ obs, const unsigned short* __restrict__ W1b,
        unsigned short* __restrict__ xs,
        const int* __restrict__ gcnt, const int2* __restrict__ ebuf,
        int* __restrict__ cursor, int* __restrict__ csr_src) {
    int tid = threadIdx.x;
    if (blockIdx.x < FILLB2) {
        int range = blockIdx.x & 7;
        int chunk = blockIdx.x >> 3;
        int cnt = gcnt[range]; if (cnt > CAP) cnt = CAP;
        int end = (chunk + 1) * CHUNK2; if (end > cnt) end = cnt;
        const int2* src = ebuf + range * CAP;
        for (int i = chunk * CHUNK2 + tid; i < end; i += 256) {
            int2 e = src[i];
            int s = atomicAdd(&cursor[e.x], 1);
            if (s < KMAX) csr_src[e.x * KMAX + s] = e.y;
        }
        return;
    }
    __shared__ char sB[64 * IND * 2];           // W1 bf16 [64][128], swizzled
    int base = (blockIdx.x - FILLB2) * 64;

    {
        const uint4* Wsrc = (const uint4*)W1b;  // 8 bf16 per uint4
        for (int idx = tid; idx < 8 * IND; idx += 256) {
            int row = idx >> 4, c8 = idx & 15;  // 16 uint4 per row
            uint4 v = Wsrc[idx];
            int byte = row * (IND * 2) + c8 * 16;
            byte ^= (row & 7) << 4;
            *(uint4*)(sB + byte) = v;
        }
    }
    __syncthreads();

    int wave = tid >> 6, lane = tid & 63;
    int r16 = lane & 15, kg = lane >> 4;
    int arow = base + 16 * wave + r16;
    if (arow >= NN) arow = NN - 1;              // clamp; writes are guarded
    const float4* Ap = (const float4*)(obs + (size_t)arow * IND) + kg * 2;

    float4 va[8];
    #pragma unroll
    for (int s = 0; s < 4; ++s) {
        va[2 * s]     = Ap[s * 8];
        va[2 * s + 1] = Ap[s * 8 + 1];
    }

    f32x4 acc[4];
    #pragma unroll
    for (int j = 0; j < 4; ++j) acc[j] = (f32x4){0.f, 0.f, 0.f, 0.f};

    #pragma unroll
    for (int s = 0; s < 4; ++s) {
        float4 v0 = va[2 * s], v1 = va[2 * s + 1];
        s16x8 a;
        a[0] = (short)f2bf(v0.x); a[1] = (short)f2bf(v0.y);
        a[2] = (short)f2bf(v0.z); a[3] = (short)f2bf(v0.w);
        a[4] = (short)f2bf(v1.x); a[5] = (short)f2bf(v1.y);
        a[6] = (short)f2bf(v1.z); a[7] = (short)f2bf(v1.w);
        int kb = (s * 32 + kg * 8) * 2;
        #pragma unroll
        for (int j = 0; j < 4; ++j) {
            int row = 16 * j + r16;
            int byte = row * (IND * 2) + kb;
            byte ^= (row & 7) << 4;
            s16x8 b = *(const s16x8*)(sB + byte);
            acc[j] = __builtin_amdgcn_mfma_f32_16x16x32_bf16(a, b, acc[j], 0, 0, 0);
        }
    }

    #pragma unroll
    for (int r = 0; r < 4; ++r) {
        int n = base + 16 * wave + kg * 4 + r;
        if (n >= NN) continue;
        #pragma unroll
        for (int j = 0; j < 4; ++j) {
            int c = 16 * j + r16;
            xs[(size_t)n * HID + c] = (unsigned short)f2bf(acc[j][r]);
        }
    }
}

// ---------------- fused agg1 + gemm2 ----------------
// Phase 1 per node (16-lane group, 4 ch/lane): index line loaded cooperatively
// (lane l16 holds slots 2*l16, 2*l16+1), __shfl-broadcast -> pipelined gathers.
// h1 = relu(dn * (self + sum xs1[r]*dr) + b1) -> swizzled LDS.
// Phase 2: MFMA h1 @ W2^T, epilogue pre-scale by dn, store bf16.
__global__ __launch_bounds__(256) void k_agg_gemm(
        const unsigned short* __restrict__ xs, const int* __restrict__ cursor,
        const int* __restrict__ csr_src, const float* __restrict__ bias,
        const unsigned short* __restrict__ W2b, unsigned short* __restrict__ xs2) {
    __shared__ char smem[2 * 64 * HID * 2];     // A + B tiles, 8 KB each
    char* sA = smem;
    char* sB = smem + 64 * HID * 2;
    int tid = threadIdx.x;
    int base = blockIdx.x * 64;

    {
        const uint4* Wsrc = (const uint4*)W2b;
        for (int idx = tid; idx < 8 * HID; idx += 256) {
            int row = idx >> 3, c8 = idx & 7;
            uint4 v = Wsrc[idx];
            int byte = row * (HID * 2) + c8 * 16;
            byte ^= (row & 7) << 4;
            *(uint4*)(sB + byte) = v;
        }
    }

    int lane = tid & 63;
    int l16 = lane & 15, gbase = lane & 48;
    int grp = tid >> 4;
    const uint2* src = (const uint2*)xs;
    const int2* csr2 = (const int2*)csr_src;    // 16 int2 per node line
    float4 bb = ((const float4*)bias)[l16];

    #pragma unroll
    for (int sub = 0; sub < 4; ++sub) {
        int row = sub * 16 + grp;
        int node = base + row;
        uint2 o; o.x = 0u; o.y = 0u;
        if (node < NN) {
            int deg = cursor[node];
            int cnt = deg < KMAX ? deg : KMAX;
            float dn = rsqrtf((float)(deg + 1));
            // self message (replaces stored self-loop)
            uint2 sv = src[(size_t)node * 16 + l16];
            float a0 = __uint_as_float(sv.x << 16) * dn;
            float a1 = __uint_as_float(sv.x & 0xFFFF0000u) * dn;
            float a2 = __uint_as_float(sv.y << 16) * dn;
            float a3 = __uint_as_float(sv.y & 0xFFFF0000u) * dn;
            int2 idx = csr2[(size_t)node * 16 + l16];
            int npairs = (cnt + 1) >> 1;
            for (int jj = 0; jj < npairs; ++jj) {
                int r0 = __shfl(idx.x, gbase + jj, 64);
                int r1 = __shfl(idx.y, gbase + jj, 64);
                float dr0 = rsqrtf((float)(cursor[r0] + 1));
                uint2 v0 = src[(size_t)r0 * 16 + l16];
                a0 += __uint_as_float(v0.x << 16) * dr0;
                a1 += __uint_as_float(v0.x & 0xFFFF0000u) * dr0;
                a2 += __uint_as_float(v0.y << 16) * dr0;
                a3 += __uint_as_float(v0.y & 0xFFFF0000u) * dr0;
                if (2 * jj + 1 < cnt) {
                    float dr1 = rsqrtf((float)(cursor[r1] + 1));
                    uint2 v1 = src[(size_t)r1 * 16 + l16];
                    a0 += __uint_as_float(v1.x << 16) * dr1;
                    a1 += __uint_as_float(v1.x & 0xFFFF0000u) * dr1;
                    a2 += __uint_as_float(v1.y << 16) * dr1;
                    a3 += __uint_as_float(v1.y & 0xFFFF0000u) * dr1;
                }
            }
            float h0 = fmaxf(fmaf(dn, a0, bb.x), 0.f);
            float h1 = fmaxf(fmaf(dn, a1, bb.y), 0.f);
            float h2 = fmaxf(fmaf(dn, a2, bb.z), 0.f);
            float h3 = fmaxf(fmaf(dn, a3, bb.w), 0.f);
            o.x = f2bf(h0) | (f2bf(h1) << 16);
            o.y = f2bf(h2) | (f2bf(h3) << 16);
        }
        int byte = row * (HID * 2) + l16 * 8;
        byte ^= (row & 7) << 4;
        *(uint2*)(sA + byte) = o;
    }
    __syncthreads();

    int wave = tid >> 6;
    int wr = wave >> 1, wc = wave & 1;
    int r16 = lane & 15, kg = lane >> 4;

    f32x4 acc[2][2];
    #pragma unroll
    for (int i = 0; i < 2; ++i)
        #pragma unroll
        for (int j = 0; j < 2; ++j)
            acc[i][j] = (f32x4){0.f, 0.f, 0.f, 0.f};

    #pragma unroll
    for (int s = 0; s < HID / 32; ++s) {
        int kb = (s * 32 + kg * 8) * 2;
        s16x8 a[2], b[2];
        #pragma unroll
        for (int i = 0; i < 2; ++i) {
            int row = 32 * wr + 16 * i + r16;
            int byte = row * (HID * 2) + kb;
            byte ^= (row & 7) << 4;
            a[i] = *(const s16x8*)(sA + byte);
        }
        #pragma unroll
        for (int j = 0; j < 2; ++j) {
            int row = 32 * wc + 16 * j + r16;
            int byte = row * (HID * 2) + kb;
            byte ^= (row & 7) << 4;
            b[j] = *(const s16x8*)(sB + byte);
        }
        #pragma unroll
        for (int i = 0; i < 2; ++i)
            #pragma unroll
            for (int j = 0; j < 2; ++j)
                acc[i][j] = __builtin_amdgcn_mfma_f32_16x16x32_bf16(a[i], b[j], acc[i][j], 0, 0, 0);
    }

    #pragma unroll
    for (int i = 0; i < 2; ++i) {
        #pragma unroll
        for (int r = 0; r < 4; ++r) {
            int n = base + 32 * wr + 16 * i + kg * 4 + r;
            if (n >= NN) continue;
            float d = rsqrtf((float)(cursor[n] + 1));   // pre-scale layer-2 source side
            #pragma unroll
            for (int j = 0; j < 2; ++j) {
                int c = 32 * wc + 16 * j + r16;
                xs2[(size_t)n * HID + c] = (unsigned short)f2bf(acc[i][j][r] * d);
            }
        }
    }
}

// ---------------- agg2 + final dot + slice (xs2 pre-scaled) ----------------
__global__ __launch_bounds__(256) void k_agg_out(const unsigned short* __restrict__ xs,
                      const int* __restrict__ cursor, const int* __restrict__ csr_src,
                      const float* __restrict__ bias, const float* __restrict__ W3,
                      const float* __restrict__ b3, float* __restrict__ outp) {
    int tid = threadIdx.x;
    int lane = tid & 63;
    int l16 = lane & 15, gbase = lane & 48;
    int node = blockIdx.x * 16 + (tid >> 4);
    if (node >= NN) return;
    int g15 = node / 15, jj15 = node - g15 * 15;
    if (jj15 < 3) return;                       // h2 of dropped nodes is unused
    int deg = cursor[node];
    int cnt = deg < KMAX ? deg : KMAX;
    float dn = rsqrtf((float)(deg + 1));
    const uint2* src = (const uint2*)xs;
    const int2* csr2 = (const int2*)csr_src;
    // self message (xs2 already carries dinv[src])
    uint2 sv = src[(size_t)node * 16 + l16];
    float a0 = __uint_as_float(sv.x << 16);
    float a1 = __uint_as_float(sv.x & 0xFFFF0000u);
    float a2 = __uint_as_float(sv.y << 16);
    float a3 = __uint_as_float(sv.y & 0xFFFF0000u);
    int2 idx = csr2[(size_t)node * 16 + l16];
    int npairs = (cnt + 1) >> 1;
    for (int jj = 0; jj < npairs; ++jj) {
        int r0 = __shfl(idx.x, gbase + jj, 64);
        int r1 = __shfl(idx.y, gbase + jj, 64);
        uint2 v0 = src[(size_t)r0 * 16 + l16];
        a0 += __uint_as_float(v0.x << 16);
        a1 += __uint_as_float(v0.x & 0xFFFF0000u);
        a2 += __uint_as_float(v0.y << 16);
        a3 += __uint_as_float(v0.y & 0xFFFF0000u);
        if (2 * jj + 1 < cnt) {
            uint2 v1 = src[(size_t)r1 * 16 + l16];
            a0 += __uint_as_float(v1.x << 16);
            a1 += __uint_as_float(v1.x & 0xFFFF0000u);
            a2 += __uint_as_float(v1.y << 16);
            a3 += __uint_as_float(v1.y & 0xFFFF0000u);
        }
    }
    float4 bb = ((const float4*)bias)[l16];
    float h0 = fmaxf(fmaf(dn, a0, bb.x), 0.f);
    float h1 = fmaxf(fmaf(dn, a1, bb.y), 0.f);
    float h2 = fmaxf(fmaf(dn, a2, bb.z), 0.f);
    float h3 = fmaxf(fmaf(dn, a3, bb.w), 0.f);
    float4 ww = ((const float4*)W3)[l16];
    float v = h0 * ww.x + h1 * ww.y + h2 * ww.z + h3 * ww.w;
    v += __shfl_xor(v, 1, 64);
    v += __shfl_xor(v, 2, 64);
    v += __shfl_xor(v, 4, 64);
    v += __shfl_xor(v, 8, 64);                  // reduce within the 16-lane group
    if (l16 == 0) outp[g15 * 12 + (jj15 - 3)] = v + b3[0];
}

extern "C" void kernel_launch(void* const* d_in, const int* in_sizes, int n_in,
                              void* d_out, int out_size, void* d_ws, size_t ws_size,
                              hipStream_t stream) {
    const float* obs = (const float*)d_in[0];
    const int*   ei  = (const int*)d_in[1];
    const float* W1  = (const float*)d_in[2];
    const float* b1  = (const float*)d_in[3];
    const float* W2  = (const float*)d_in[4];
    const float* b2  = (const float*)d_in[5];
    const float* W3  = (const float*)d_in[6];
    const float* b3  = (const float*)d_in[7];
    float* out = (float*)d_out;

    char* ws = (char*)d_ws;
    size_t off = 0;
    auto alloc = [&](size_t bytes) -> void* {
        void* p = ws + off;
        off += (bytes + 255) & ~(size_t)255;
        return p;
    };
    int*   gcnt    = (int*)  alloc(RANGES * 4);
    int*   cursor  = (int*)  alloc((size_t)NN * 4);
    int*   csr_src = (int*)  alloc((size_t)NN * KMAX * 4);     // 19.2 MB bucketed CSR
    int2*  ebuf    = (int2*) alloc((size_t)RANGES * CAP * 8);  // 5 MB partitioned edges
    unsigned short* XB  = (unsigned short*)alloc((size_t)NN * HID * 2);
    unsigned short* XB2 = (unsigned short*)alloc((size_t)NN * HID * 2);
    unsigned short* W1b = (unsigned short*)alloc((size_t)HID * IND * 2);
    unsigned short* W2b = (unsigned short*)alloc((size_t)HID * HID * 2);

    const int* rowv = ei;
    const int* colv = ei + NE;

    hipMemsetAsync(gcnt, 0, RANGES * 4, stream);
    k_init<<<PARTB + ZEROB, 256, 0, stream>>>(rowv, colv, gcnt, ebuf,
                                              cursor, W1, W2, W1b, W2b);
    k_fill_gemm1<<<FILLB2 + GEMM_GRID, 256, 0, stream>>>(obs, W1b, XB,
                                                         gcnt, ebuf, cursor, csr_src);
    k_agg_gemm<<<GEMM_GRID, 256, 0, stream>>>(XB, cursor, csr_src, b1, W2b, XB2);
    k_agg_out<<<(NN + 15) / 16, 256, 0, stream>>>(XB2, cursor, csr_src, b2, W3, b3, out);
}

// Round 13
// 117.310 us; speedup vs baseline: 1.0699x; 1.0699x over previous
//
#include <hip/hip_runtime.h>

#define NN 150000
#define NE 600000
#define IND 128
#define HID 64
#define KMAX 32            // CSR bucket stride; in-deg ~Poisson(4), P(>32) ~ 1e-19
#define BSHIFT 9
#define NBUCK 293          // ceil(NN / 512)
#define SUBCAP 384         // per-(bucket,xcd) edge cap; mean 256, +8 sigma
#define PARTB 586          // ceil(NE/4 / 256) partition blocks
#define CVTB 32            // W-convert blocks
#define GEMM_GRID ((NN + 63) / 64)       // 2344

typedef short s16x8 __attribute__((ext_vector_type(8)));
typedef float f32x4 __attribute__((ext_vector_type(4)));

__device__ __forceinline__ unsigned f2bf(float f) {
    unsigned u = __float_as_uint(f);
    return (u + 0x7FFFu + ((u >> 16) & 1u)) >> 16;   // RNE
}

// ---------------- hetero init: edge partition (Phase A) + W->bf16 ----------------
// Phase A blocks: stream edge quads once; LDS-histogram by dst bucket (dst>>9);
// ONE reservation atomic per bucket per block (to per-(bucket,xcd) counter);
// per-edge slots via LDS atomics; write (dst,src) runs into the block's XCD
// sub-window. No per-edge global atomics.
__global__ __launch_bounds__(256) void k_init(
        const int* __restrict__ rowv, const int* __restrict__ colv,
        int* __restrict__ gcnt, int2* __restrict__ ebuf,
        const float* __restrict__ W1, const float* __restrict__ W2,
        unsigned short* __restrict__ W1b, unsigned short* __restrict__ W2b) {
    int tid = threadIdx.x;
    if (blockIdx.x < PARTB) {
        __shared__ int hist[NBUCK];
        __shared__ int bases[NBUCK];
        for (int i = tid; i < NBUCK; i += 256) hist[i] = 0;
        __syncthreads();
        int t = blockIdx.x * 256 + tid;
        bool valid = (t < NE / 4);
        int4 r4, c4;
        int bk[4], sl[4];
        if (valid) {
            r4 = ((const int4*)rowv)[t];
            c4 = ((const int4*)colv)[t];
            bk[0] = c4.x >> BSHIFT; sl[0] = atomicAdd(&hist[bk[0]], 1);
            bk[1] = c4.y >> BSHIFT; sl[1] = atomicAdd(&hist[bk[1]], 1);
            bk[2] = c4.z >> BSHIFT; sl[2] = atomicAdd(&hist[bk[2]], 1);
            bk[3] = c4.w >> BSHIFT; sl[3] = atomicAdd(&hist[bk[3]], 1);
        }
        __syncthreads();
        int xcd = blockIdx.x & 7;
        for (int i = tid; i < NBUCK; i += 256)
            bases[i] = hist[i] ? atomicAdd(&gcnt[i * 8 + xcd], hist[i]) : 0;
        __syncthreads();
        if (valid) {
            #pragma unroll
            for (int e = 0; e < 4; ++e) {
                int c = (e == 0) ? c4.x : (e == 1) ? c4.y : (e == 2) ? c4.z : c4.w;
                int r = (e == 0) ? r4.x : (e == 1) ? r4.y : (e == 2) ? r4.z : r4.w;
                int p = bases[bk[e]] + sl[e];
                if (p < SUBCAP) ebuf[(bk[e] * 8 + xcd) * SUBCAP + p] = make_int2(c, r);
            }
        }
        return;
    }
    int t = (blockIdx.x - PARTB) * 256 + tid;
    if (t < HID * IND) W1b[t] = (unsigned short)f2bf(W1[t]);
    if (t < HID * HID) W2b[t] = (unsigned short)f2bf(W2[t]);
}

// ---------------- hetero: Phase-B bucket sort (LDS cursors, no atomics) + gemm1 ----------------
// Sort blocks (b < NBUCK): block k exclusively owns nodes [k*512, k*512+512).
// Reads its 8 compacted sub-runs, places edges via LDS per-node cursors into its
// private 64 KB csr window, writes exact degrees to cursor[]. Zero global atomics.
// gemm1: xs[n][c] = bf16( sum_k obs[n][k]*W1[c][k] ) -- UNSCALED (dinv on gather).
// wave = 16 rows x 64 cols; A direct from global; W1 in LDS 16 KB XOR-swizzled.
__global__ __launch_bounds__(256) void k_sort_gemm1(
        const float* __restrict__ obs, const unsigned short* __restrict__ W1b,
        unsigned short* __restrict__ xs,
        const int* __restrict__ gcnt, const int2* __restrict__ ebuf,
        int* __restrict__ cursor, int* __restrict__ csr_src) {
    __shared__ char smem[64 * IND * 2];         // gemm: W1 tile; sort: LDS cursors
    int tid = threadIdx.x;
    if (blockIdx.x < NBUCK) {
        int k = blockIdx.x;
        int lo = k << BSHIFT;
        int* cnt = (int*)smem;
        for (int i = tid; i < 512; i += 256) cnt[i] = 0;
        __syncthreads();
        for (int x = 0; x < 8; ++x) {
            int len = gcnt[k * 8 + x]; if (len > SUBCAP) len = SUBCAP;
            const int2* run = ebuf + (size_t)(k * 8 + x) * SUBCAP;
            for (int i = tid; i < len; i += 256) {
                int2 e = run[i];
                int s = atomicAdd(&cnt[e.x - lo], 1);       // LDS atomic
                if (s < KMAX) csr_src[e.x * KMAX + s] = e.y;
            }
        }
        __syncthreads();
        for (int i = tid; i < 512; i += 256) {
            int n = lo + i;
            if (n < NN) cursor[n] = cnt[i];
        }
        return;
    }
    char* sB = smem;
    int base = (blockIdx.x - NBUCK) * 64;

    {
        const uint4* Wsrc = (const uint4*)W1b;  // 8 bf16 per uint4
        for (int idx = tid; idx < 8 * IND; idx += 256) {
            int row = idx >> 4, c8 = idx & 15;  // 16 uint4 per row
            uint4 v = Wsrc[idx];
            int byte = row * (IND * 2) + c8 * 16;
            byte ^= (row & 7) << 4;
            *(uint4*)(sB + byte) = v;
        }
    }
    __syncthreads();

    int wave = tid >> 6, lane = tid & 63;
    int r16 = lane & 15, kg = lane >> 4;
    int arow = base + 16 * wave + r16;
    if (arow >= NN) arow = NN - 1;              // clamp; writes are guarded
    const float4* Ap = (const float4*)(obs + (size_t)arow * IND) + kg * 2;

    float4 va[8];
    #pragma unroll
    for (int s = 0; s < 4; ++s) {
        va[2 * s]     = Ap[s * 8];
        va[2 * s + 1] = Ap[s * 8 + 1];
    }

    f32x4 acc[4];
    #pragma unroll
    for (int j = 0; j < 4; ++j) acc[j] = (f32x4){0.f, 0.f, 0.f, 0.f};

    #pragma unroll
    for (int s = 0; s < 4; ++s) {
        float4 v0 = va[2 * s], v1 = va[2 * s + 1];
        s16x8 a;
        a[0] = (short)f2bf(v0.x); a[1] = (short)f2bf(v0.y);
        a[2] = (short)f2bf(v0.z); a[3] = (short)f2bf(v0.w);
        a[4] = (short)f2bf(v1.x); a[5] = (short)f2bf(v1.y);
        a[6] = (short)f2bf(v1.z); a[7] = (short)f2bf(v1.w);
        int kb = (s * 32 + kg * 8) * 2;
        #pragma unroll
        for (int j = 0; j < 4; ++j) {
            int row = 16 * j + r16;
            int byte = row * (IND * 2) + kb;
            byte ^= (row & 7) << 4;
            s16x8 b = *(const s16x8*)(sB + byte);
            acc[j] = __builtin_amdgcn_mfma_f32_16x16x32_bf16(a, b, acc[j], 0, 0, 0);
        }
    }

    #pragma unroll
    for (int r = 0; r < 4; ++r) {
        int n = base + 16 * wave + kg * 4 + r;
        if (n >= NN) continue;
        #pragma unroll
        for (int j = 0; j < 4; ++j) {
            int c = 16 * j + r16;
            xs[(size_t)n * HID + c] = (unsigned short)f2bf(acc[j][r]);
        }
    }
}

// ---------------- fused agg1 + gemm2 (unchanged from R11) ----------------
__global__ __launch_bounds__(256) void k_agg_gemm(
        const unsigned short* __restrict__ xs, const int* __restrict__ cursor,
        const int* __restrict__ csr_src, const float* __restrict__ bias,
        const unsigned short* __restrict__ W2b, unsigned short* __restrict__ xs2) {
    __shared__ char smem[2 * 64 * HID * 2];     // A + B tiles, 8 KB each
    char* sA = smem;
    char* sB = smem + 64 * HID * 2;
    int tid = threadIdx.x;
    int base = blockIdx.x * 64;

    {
        const uint4* Wsrc = (const uint4*)W2b;
        for (int idx = tid; idx < 8 * HID; idx += 256) {
            int row = idx >> 3, c8 = idx & 7;
            uint4 v = Wsrc[idx];
            int byte = row * (HID * 2) + c8 * 16;
            byte ^= (row & 7) << 4;
            *(uint4*)(sB + byte) = v;
        }
    }

    int lane = tid & 63;
    int l16 = lane & 15, gbase = lane & 48;
    int grp = tid >> 4;
    const uint2* src = (const uint2*)xs;
    const int2* csr2 = (const int2*)csr_src;    // 16 int2 per node line
    float4 bb = ((const float4*)bias)[l16];

    #pragma unroll
    for (int sub = 0; sub < 4; ++sub) {
        int row = sub * 16 + grp;
        int node = base + row;
        uint2 o; o.x = 0u; o.y = 0u;
        if (node < NN) {
            int deg = cursor[node];
            int cnt = deg < KMAX ? deg : KMAX;
            float dn = rsqrtf((float)(deg + 1));
            // self message (replaces stored self-loop)
            uint2 sv = src[(size_t)node * 16 + l16];
            float a0 = __uint_as_float(sv.x << 16) * dn;
            float a1 = __uint_as_float(sv.x & 0xFFFF0000u) * dn;
            float a2 = __uint_as_float(sv.y << 16) * dn;
            float a3 = __uint_as_float(sv.y & 0xFFFF0000u) * dn;
            int2 idx = csr2[(size_t)node * 16 + l16];
            int npairs = (cnt + 1) >> 1;
            for (int jj = 0; jj < npairs; ++jj) {
                int r0 = __shfl(idx.x, gbase + jj, 64);
                int r1 = __shfl(idx.y, gbase + jj, 64);
                float dr0 = rsqrtf((float)(cursor[r0] + 1));
                uint2 v0 = src[(size_t)r0 * 16 + l16];
                a0 += __uint_as_float(v0.x << 16) * dr0;
                a1 += __uint_as_float(v0.x & 0xFFFF0000u) * dr0;
                a2 += __uint_as_float(v0.y << 16) * dr0;
                a3 += __uint_as_float(v0.y & 0xFFFF0000u) * dr0;
                if (2 * jj + 1 < cnt) {
                    float dr1 = rsqrtf((float)(cursor[r1] + 1));
                    uint2 v1 = src[(size_t)r1 * 16 + l16];
                    a0 += __uint_as_float(v1.x << 16) * dr1;
                    a1 += __uint_as_float(v1.x & 0xFFFF0000u) * dr1;
                    a2 += __uint_as_float(v1.y << 16) * dr1;
                    a3 += __uint_as_float(v1.y & 0xFFFF0000u) * dr1;
                }
            }
            float h0 = fmaxf(fmaf(dn, a0, bb.x), 0.f);
            float h1 = fmaxf(fmaf(dn, a1, bb.y), 0.f);
            float h2 = fmaxf(fmaf(dn, a2, bb.z), 0.f);
            float h3 = fmaxf(fmaf(dn, a3, bb.w), 0.f);
            o.x = f2bf(h0) | (f2bf(h1) << 16);
            o.y = f2bf(h2) | (f2bf(h3) << 16);
        }
        int byte = row * (HID * 2) + l16 * 8;
        byte ^= (row & 7) << 4;
        *(uint2*)(sA + byte) = o;
    }
    __syncthreads();

    int wave = tid >> 6;
    int wr = wave >> 1, wc = wave & 1;
    int r16 = lane & 15, kg = lane >> 4;

    f32x4 acc[2][2];
    #pragma unroll
    for (int i = 0; i < 2; ++i)
        #pragma unroll
        for (int j = 0; j < 2; ++j)
            acc[i][j] = (f32x4){0.f, 0.f, 0.f, 0.f};

    #pragma unroll
    for (int s = 0; s < HID / 32; ++s) {
        int kb = (s * 32 + kg * 8) * 2;
        s16x8 a[2], b[2];
        #pragma unroll
        for (int i = 0; i < 2; ++i) {
            int row = 32 * wr + 16 * i + r16;
            int byte = row * (HID * 2) + kb;
            byte ^= (row & 7) << 4;
            a[i] = *(const s16x8*)(sA + byte);
        }
        #pragma unroll
        for (int j = 0; j < 2; ++j) {
            int row = 32 * wc + 16 * j + r16;
            int byte = row * (HID * 2) + kb;
            byte ^= (row & 7) << 4;
            b[j] = *(const s16x8*)(sB + byte);
        }
        #pragma unroll
        for (int i = 0; i < 2; ++i)
            #pragma unroll
            for (int j = 0; j < 2; ++j)
                acc[i][j] = __builtin_amdgcn_mfma_f32_16x16x32_bf16(a[i], b[j], acc[i][j], 0, 0, 0);
    }

    #pragma unroll
    for (int i = 0; i < 2; ++i) {
        #pragma unroll
        for (int r = 0; r < 4; ++r) {
            int n = base + 32 * wr + 16 * i + kg * 4 + r;
            if (n >= NN) continue;
            float d = rsqrtf((float)(cursor[n] + 1));   // pre-scale layer-2 source side
            #pragma unroll
            for (int j = 0; j < 2; ++j) {
                int c = 32 * wc + 16 * j + r16;
                xs2[(size_t)n * HID + c] = (unsigned short)f2bf(acc[i][j][r] * d);
            }
        }
    }
}

// ---------------- agg2 + final dot + slice (unchanged from R11) ----------------
__global__ __launch_bounds__(256) void k_agg_out(const unsigned short* __restrict__ xs,
                      const int* __restrict__ cursor, const int* __restrict__ csr_src,
                      const float* __restrict__ bias, const float* __restrict__ W3,
                      const float* __restrict__ b3, float* __restrict__ outp) {
    int tid = threadIdx.x;
    int lane = tid & 63;
    int l16 = lane & 15, gbase = lane & 48;
    int node = blockIdx.x * 16 + (tid >> 4);
    if (node >= NN) return;
    int g15 = node / 15, jj15 = node - g15 * 15;
    if (jj15 < 3) return;                       // h2 of dropped nodes is unused
    int deg = cursor[node];
    int cnt = deg < KMAX ? deg : KMAX;
    float dn = rsqrtf((float)(deg + 1));
    const uint2* src = (const uint2*)xs;
    const int2* csr2 = (const int2*)csr_src;
    // self message (xs2 already carries dinv[src])
    uint2 sv = src[(size_t)node * 16 + l16];
    float a0 = __uint_as_float(sv.x << 16);
    float a1 = __uint_as_float(sv.x & 0xFFFF0000u);
    float a2 = __uint_as_float(sv.y << 16);
    float a3 = __uint_as_float(sv.y & 0xFFFF0000u);
    int2 idx = csr2[(size_t)node * 16 + l16];
    int npairs = (cnt + 1) >> 1;
    for (int jj = 0; jj < npairs; ++jj) {
        int r0 = __shfl(idx.x, gbase + jj, 64);
        int r1 = __shfl(idx.y, gbase + jj, 64);
        uint2 v0 = src[(size_t)r0 * 16 + l16];
        a0 += __uint_as_float(v0.x << 16);
        a1 += __uint_as_float(v0.x & 0xFFFF0000u);
        a2 += __uint_as_float(v0.y << 16);
        a3 += __uint_as_float(v0.y & 0xFFFF0000u);
        if (2 * jj + 1 < cnt) {
            uint2 v1 = src[(size_t)r1 * 16 + l16];
            a0 += __uint_as_float(v1.x << 16);
            a1 += __uint_as_float(v1.x & 0xFFFF0000u);
            a2 += __uint_as_float(v1.y << 16);
            a3 += __uint_as_float(v1.y & 0xFFFF0000u);
        }
    }
    float4 bb = ((const float4*)bias)[l16];
    float h0 = fmaxf(fmaf(dn, a0, bb.x), 0.f);
    float h1 = fmaxf(fmaf(dn, a1, bb.y), 0.f);
    float h2 = fmaxf(fmaf(dn, a2, bb.z), 0.f);
    float h3 = fmaxf(fmaf(dn, a3, bb.w), 0.f);
    float4 ww = ((const float4*)W3)[l16];
    float v = h0 * ww.x + h1 * ww.y + h2 * ww.z + h3 * ww.w;
    v += __shfl_xor(v, 1, 64);
    v += __shfl_xor(v, 2, 64);
    v += __shfl_xor(v, 4, 64);
    v += __shfl_xor(v, 8, 64);                  // reduce within the 16-lane group
    if (l16 == 0) outp[g15 * 12 + (jj15 - 3)] = v + b3[0];
}

extern "C" void kernel_launch(void* const* d_in, const int* in_sizes, int n_in,
                              void* d_out, int out_size, void* d_ws, size_t ws_size,
                              hipStream_t stream) {
    const float* obs = (const float*)d_in[0];
    const int*   ei  = (const int*)d_in[1];
    const float* W1  = (const float*)d_in[2];
    const float* b1  = (const float*)d_in[3];
    const float* W2  = (const float*)d_in[4];
    const float* b2  = (const float*)d_in[5];
    const float* W3  = (const float*)d_in[6];
    const float* b3  = (const float*)d_in[7];
    float* out = (float*)d_out;

    char* ws = (char*)d_ws;
    size_t off = 0;
    auto alloc = [&](size_t bytes) -> void* {
        void* p = ws + off;
        off += (bytes + 255) & ~(size_t)255;
        return p;
    };
    int*   gcnt    = (int*)  alloc((size_t)NBUCK * 8 * 4);          // 9.4 KB
    int*   cursor  = (int*)  alloc((size_t)NN * 4);
    int*   csr_src = (int*)  alloc((size_t)NN * KMAX * 4);          // 19.2 MB
    int2*  ebuf    = (int2*) alloc((size_t)NBUCK * 8 * SUBCAP * 8); // 7.2 MB
    unsigned short* XB  = (unsigned short*)alloc((size_t)NN * HID * 2);
    unsigned short* XB2 = (unsigned short*)alloc((size_t)NN * HID * 2);
    unsigned short* W1b = (unsigned short*)alloc((size_t)HID * IND * 2);
    unsigned short* W2b = (unsigned short*)alloc((size_t)HID * HID * 2);

    const int* rowv = ei;
    const int* colv = ei + NE;

    hipMemsetAsync(gcnt, 0, (size_t)NBUCK * 8 * 4, stream);
    k_init<<<PARTB + CVTB, 256, 0, stream>>>(rowv, colv, gcnt, ebuf, W1, W2, W1b, W2b);
    k_sort_gemm1<<<NBUCK + GEMM_GRID, 256, 0, stream>>>(obs, W1b, XB,
                                                        gcnt, ebuf, cursor, csr_src);
    k_agg_gemm<<<GEMM_GRID, 256, 0, stream>>>(XB, cursor, csr_src, b1, W2b, XB2);
    k_agg_out<<<(NN + 15) / 16, 256, 0, stream>>>(XB2, cursor, csr_src, b2, W3, b3, out);
}

// Round 14
// 114.813 us; speedup vs baseline: 1.0932x; 1.0217x over previous
//
#include <hip/hip_runtime.h>

#define NN 150000
#define NE 600000
#define IND 128
#define HID 64
#define KMAX 32            // CSR bucket stride; in-deg ~Poisson(4), P(>32) ~ 1e-19
#define BSHIFT 9
#define NBUCK 293          // ceil(NN / 512)
#define SUBCAP 384         // per-(bucket,xcd) edge cap; mean 256, +8 sigma
#define PARTB 586          // ceil(NE/4 / 256) partition blocks
#define CVTB 32            // W-convert blocks
#define GEMM_GRID ((NN + 63) / 64)       // 2344

typedef short s16x8 __attribute__((ext_vector_type(8)));
typedef float f32x4 __attribute__((ext_vector_type(4)));

__device__ __forceinline__ unsigned f2bf(float f) {
    unsigned u = __float_as_uint(f);
    return (u + 0x7FFFu + ((u >> 16) & 1u)) >> 16;   // RNE
}

#define ACC4(v, dr) \
    a0 = fmaf(__uint_as_float((v).x << 16), dr, a0); \
    a1 = fmaf(__uint_as_float((v).x & 0xFFFF0000u), dr, a1); \
    a2 = fmaf(__uint_as_float((v).y << 16), dr, a2); \
    a3 = fmaf(__uint_as_float((v).y & 0xFFFF0000u), dr, a3);

// ---------------- hetero init: edge partition (Phase A) + W->bf16 ----------------
__global__ __launch_bounds__(256) void k_init(
        const int* __restrict__ rowv, const int* __restrict__ colv,
        int* __restrict__ gcnt, int2* __restrict__ ebuf,
        const float* __restrict__ W1, const float* __restrict__ W2,
        unsigned short* __restrict__ W1b, unsigned short* __restrict__ W2b) {
    int tid = threadIdx.x;
    if (blockIdx.x < PARTB) {
        __shared__ int hist[NBUCK];
        __shared__ int bases[NBUCK];
        for (int i = tid; i < NBUCK; i += 256) hist[i] = 0;
        __syncthreads();
        int t = blockIdx.x * 256 + tid;
        bool valid = (t < NE / 4);
        int4 r4, c4;
        int bk[4], sl[4];
        if (valid) {
            r4 = ((const int4*)rowv)[t];
            c4 = ((const int4*)colv)[t];
            bk[0] = c4.x >> BSHIFT; sl[0] = atomicAdd(&hist[bk[0]], 1);
            bk[1] = c4.y >> BSHIFT; sl[1] = atomicAdd(&hist[bk[1]], 1);
            bk[2] = c4.z >> BSHIFT; sl[2] = atomicAdd(&hist[bk[2]], 1);
            bk[3] = c4.w >> BSHIFT; sl[3] = atomicAdd(&hist[bk[3]], 1);
        }
        __syncthreads();
        int xcd = blockIdx.x & 7;
        for (int i = tid; i < NBUCK; i += 256)
            bases[i] = hist[i] ? atomicAdd(&gcnt[i * 8 + xcd], hist[i]) : 0;
        __syncthreads();
        if (valid) {
            #pragma unroll
            for (int e = 0; e < 4; ++e) {
                int c = (e == 0) ? c4.x : (e == 1) ? c4.y : (e == 2) ? c4.z : c4.w;
                int r = (e == 0) ? r4.x : (e == 1) ? r4.y : (e == 2) ? r4.z : r4.w;
                int p = bases[bk[e]] + sl[e];
                if (p < SUBCAP) ebuf[(bk[e] * 8 + xcd) * SUBCAP + p] = make_int2(c, r);
            }
        }
        return;
    }
    int t = (blockIdx.x - PARTB) * 256 + tid;
    if (t < HID * IND) W1b[t] = (unsigned short)f2bf(W1[t]);
    if (t < HID * HID) W2b[t] = (unsigned short)f2bf(W2[t]);
}

// ---------------- hetero: Phase-B bucket sort (LDS cursors) + gemm1 ----------------
// Sort blocks own 512 nodes exclusively; LDS per-node cursors; write degrees AND
// dinvf = rsqrt(deg+1). gemm1: xs = bf16(obs @ W1^T) UNSCALED.
__global__ __launch_bounds__(256) void k_sort_gemm1(
        const float* __restrict__ obs, const unsigned short* __restrict__ W1b,
        unsigned short* __restrict__ xs,
        const int* __restrict__ gcnt, const int2* __restrict__ ebuf,
        int* __restrict__ cursor, float* __restrict__ dinvf,
        int* __restrict__ csr_src) {
    __shared__ char smem[64 * IND * 2];         // gemm: W1 tile; sort: LDS cursors
    int tid = threadIdx.x;
    if (blockIdx.x < NBUCK) {
        int k = blockIdx.x;
        int lo = k << BSHIFT;
        int* cnt = (int*)smem;
        for (int i = tid; i < 512; i += 256) cnt[i] = 0;
        __syncthreads();
        for (int x = 0; x < 8; ++x) {
            int len = gcnt[k * 8 + x]; if (len > SUBCAP) len = SUBCAP;
            const int2* run = ebuf + (size_t)(k * 8 + x) * SUBCAP;
            for (int i = tid; i < len; i += 256) {
                int2 e = run[i];
                int s = atomicAdd(&cnt[e.x - lo], 1);       // LDS atomic
                if (s < KMAX) csr_src[e.x * KMAX + s] = e.y;
            }
        }
        __syncthreads();
        for (int i = tid; i < 512; i += 256) {
            int n = lo + i;
            if (n < NN) {
                cursor[n] = cnt[i];
                dinvf[n] = rsqrtf((float)(cnt[i] + 1));
            }
        }
        return;
    }
    char* sB = smem;
    int base = (blockIdx.x - NBUCK) * 64;

    {
        const uint4* Wsrc = (const uint4*)W1b;  // 8 bf16 per uint4
        for (int idx = tid; idx < 8 * IND; idx += 256) {
            int row = idx >> 4, c8 = idx & 15;
            uint4 v = Wsrc[idx];
            int byte = row * (IND * 2) + c8 * 16;
            byte ^= (row & 7) << 4;
            *(uint4*)(sB + byte) = v;
        }
    }
    __syncthreads();

    int wave = tid >> 6, lane = tid & 63;
    int r16 = lane & 15, kg = lane >> 4;
    int arow = base + 16 * wave + r16;
    if (arow >= NN) arow = NN - 1;
    const float4* Ap = (const float4*)(obs + (size_t)arow * IND) + kg * 2;

    float4 va[8];
    #pragma unroll
    for (int s = 0; s < 4; ++s) {
        va[2 * s]     = Ap[s * 8];
        va[2 * s + 1] = Ap[s * 8 + 1];
    }

    f32x4 acc[4];
    #pragma unroll
    for (int j = 0; j < 4; ++j) acc[j] = (f32x4){0.f, 0.f, 0.f, 0.f};

    #pragma unroll
    for (int s = 0; s < 4; ++s) {
        float4 v0 = va[2 * s], v1 = va[2 * s + 1];
        s16x8 a;
        a[0] = (short)f2bf(v0.x); a[1] = (short)f2bf(v0.y);
        a[2] = (short)f2bf(v0.z); a[3] = (short)f2bf(v0.w);
        a[4] = (short)f2bf(v1.x); a[5] = (short)f2bf(v1.y);
        a[6] = (short)f2bf(v1.z); a[7] = (short)f2bf(v1.w);
        int kb = (s * 32 + kg * 8) * 2;
        #pragma unroll
        for (int j = 0; j < 4; ++j) {
            int row = 16 * j + r16;
            int byte = row * (IND * 2) + kb;
            byte ^= (row & 7) << 4;
            s16x8 b = *(const s16x8*)(sB + byte);
            acc[j] = __builtin_amdgcn_mfma_f32_16x16x32_bf16(a, b, acc[j], 0, 0, 0);
        }
    }

    #pragma unroll
    for (int r = 0; r < 4; ++r) {
        int n = base + 16 * wave + kg * 4 + r;
        if (n >= NN) continue;
        #pragma unroll
        for (int j = 0; j < 4; ++j) {
            int c = 16 * j + r16;
            xs[(size_t)n * HID + c] = (unsigned short)f2bf(acc[j][r]);
        }
    }
}

// ---------------- fused agg1 + gemm2 (MLP-first gather) ----------------
// Per node (16-lane group): 64B csr idx load (slots 0..15), upfront dinvf gather
// (one per slot, shfl-broadcast per edge), unroll-8 predicated gather loop,
// rare tails for deg in (8,16] and (16,32]. h1 -> swizzled LDS -> MFMA @ W2^T.
__global__ __launch_bounds__(256) void k_agg_gemm(
        const unsigned short* __restrict__ xs, const int* __restrict__ cursor,
        const float* __restrict__ dinvf, const int* __restrict__ csr_src,
        const float* __restrict__ bias, const unsigned short* __restrict__ W2b,
        unsigned short* __restrict__ xs2) {
    __shared__ char smem[2 * 64 * HID * 2];
    char* sA = smem;
    char* sB = smem + 64 * HID * 2;
    int tid = threadIdx.x;
    int base = blockIdx.x * 64;

    {
        const uint4* Wsrc = (const uint4*)W2b;
        for (int idx = tid; idx < 8 * HID; idx += 256) {
            int row = idx >> 3, c8 = idx & 7;
            uint4 v = Wsrc[idx];
            int byte = row * (HID * 2) + c8 * 16;
            byte ^= (row & 7) << 4;
            *(uint4*)(sB + byte) = v;
        }
    }

    int lane = tid & 63;
    int l16 = lane & 15, gbase = lane & 48;
    int grp = tid >> 4;
    const uint2* src = (const uint2*)xs;
    float4 bb = ((const float4*)bias)[l16];

    int degA[4], cntA[4], idxA[4];
    uint2 svA[4];
    float drA[4];
    #pragma unroll
    for (int s4 = 0; s4 < 4; ++s4) {
        int node = base + s4 * 16 + grp;
        bool ok = node < NN;
        int nc = ok ? node : NN - 1;
        int deg = cursor[nc];
        degA[s4] = deg;
        cntA[s4] = ok ? (deg < KMAX ? deg : KMAX) : 0;
        idxA[s4] = csr_src[nc * KMAX + l16];    // 64B/group: slots 0..15
        svA[s4]  = src[(size_t)nc * 16 + l16];  // self row
    }
    #pragma unroll
    for (int s4 = 0; s4 < 4; ++s4) {
        int safe = (l16 < cntA[s4]) ? idxA[s4] : 0;
        drA[s4] = dinvf[safe];                  // dr for this lane's slot
    }

    #pragma unroll
    for (int s4 = 0; s4 < 4; ++s4) {
        int row = s4 * 16 + grp;
        int node = base + row;
        int cnt = cntA[s4];
        float dn = rsqrtf((float)(degA[s4] + 1));
        uint2 sv = svA[s4];
        float a0 = __uint_as_float(sv.x << 16) * dn;
        float a1 = __uint_as_float(sv.x & 0xFFFF0000u) * dn;
        float a2 = __uint_as_float(sv.y << 16) * dn;
        float a3 = __uint_as_float(sv.y & 0xFFFF0000u) * dn;
        #pragma unroll
        for (int j = 0; j < 8; ++j) {
            int r    = __shfl(idxA[s4], gbase + j, 64);
            float dr = __shfl(drA[s4], gbase + j, 64);
            if (j < cnt) {
                uint2 v = src[(size_t)r * 16 + l16];
                ACC4(v, dr)
            }
        }
        if (cnt > 8) {
            int c16 = cnt < 16 ? cnt : 16;
            for (int j = 8; j < c16; ++j) {
                int r    = __shfl(idxA[s4], gbase + j, 64);
                float dr = __shfl(drA[s4], gbase + j, 64);
                uint2 v = src[(size_t)r * 16 + l16];
                ACC4(v, dr)
            }
            for (int j = 16; j < cnt; ++j) {    // ultra-rare
                int r = csr_src[node * KMAX + j];
                float dr = dinvf[r];
                uint2 v = src[(size_t)r * 16 + l16];
                ACC4(v, dr)
            }
        }
        float h0 = fmaxf(fmaf(dn, a0, bb.x), 0.f);
        float h1 = fmaxf(fmaf(dn, a1, bb.y), 0.f);
        float h2 = fmaxf(fmaf(dn, a2, bb.z), 0.f);
        float h3 = fmaxf(fmaf(dn, a3, bb.w), 0.f);
        uint2 o;
        o.x = f2bf(h0) | (f2bf(h1) << 16);
        o.y = f2bf(h2) | (f2bf(h3) << 16);
        if (node >= NN) { o.x = 0u; o.y = 0u; }
        int byte = row * (HID * 2) + l16 * 8;
        byte ^= (row & 7) << 4;
        *(uint2*)(sA + byte) = o;
    }
    __syncthreads();

    int wave = tid >> 6;
    int wr = wave >> 1, wc = wave & 1;
    int r16 = lane & 15, kg = lane >> 4;

    f32x4 acc[2][2];
    #pragma unroll
    for (int i = 0; i < 2; ++i)
        #pragma unroll
        for (int j = 0; j < 2; ++j)
            acc[i][j] = (f32x4){0.f, 0.f, 0.f, 0.f};

    #pragma unroll
    for (int s = 0; s < HID / 32; ++s) {
        int kb = (s * 32 + kg * 8) * 2;
        s16x8 a[2], b[2];
        #pragma unroll
        for (int i = 0; i < 2; ++i) {
            int row = 32 * wr + 16 * i + r16;
            int byte = row * (HID * 2) + kb;
            byte ^= (row & 7) << 4;
            a[i] = *(const s16x8*)(sA + byte);
        }
        #pragma unroll
        for (int j = 0; j < 2; ++j) {
            int row = 32 * wc + 16 * j + r16;
            int byte = row * (HID * 2) + kb;
            byte ^= (row & 7) << 4;
            b[j] = *(const s16x8*)(sB + byte);
        }
        #pragma unroll
        for (int i = 0; i < 2; ++i)
            #pragma unroll
            for (int j = 0; j < 2; ++j)
                acc[i][j] = __builtin_amdgcn_mfma_f32_16x16x32_bf16(a[i], b[j], acc[i][j], 0, 0, 0);
    }

    #pragma unroll
    for (int i = 0; i < 2; ++i) {
        #pragma unroll
        for (int r = 0; r < 4; ++r) {
            int n = base + 32 * wr + 16 * i + kg * 4 + r;
            if (n >= NN) continue;
            float d = rsqrtf((float)(cursor[n] + 1));   // pre-scale layer-2 source side
            #pragma unroll
            for (int j = 0; j < 2; ++j) {
                int c = 32 * wc + 16 * j + r16;
                xs2[(size_t)n * HID + c] = (unsigned short)f2bf(acc[i][j][r] * d);
            }
        }
    }
}

// ---------------- agg2 + final dot + slice (xs2 pre-scaled; MLP gather) ----------------
__global__ __launch_bounds__(256) void k_agg_out(const unsigned short* __restrict__ xs,
                      const int* __restrict__ cursor, const int* __restrict__ csr_src,
                      const float* __restrict__ bias, const float* __restrict__ W3,
                      const float* __restrict__ b3, float* __restrict__ outp) {
    int tid = threadIdx.x;
    int lane = tid & 63;
    int l16 = lane & 15, gbase = lane & 48;
    int node = blockIdx.x * 16 + (tid >> 4);
    if (node >= NN) return;
    int g15 = node / 15, jj15 = node - g15 * 15;
    if (jj15 < 3) return;                       // h2 of dropped nodes is unused
    int deg = cursor[node];
    int cnt = deg < KMAX ? deg : KMAX;
    float dn = rsqrtf((float)(deg + 1));
    const uint2* src = (const uint2*)xs;
    int idx0 = csr_src[node * KMAX + l16];      // 64B: slots 0..15
    uint2 sv = src[(size_t)node * 16 + l16];
    float a0 = __uint_as_float(sv.x << 16);
    float a1 = __uint_as_float(sv.x & 0xFFFF0000u);
    float a2 = __uint_as_float(sv.y << 16);
    float a3 = __uint_as_float(sv.y & 0xFFFF0000u);
    #pragma unroll
    for (int j = 0; j < 8; ++j) {
        int r = __shfl(idx0, gbase + j, 64);
        if (j < cnt) {
            uint2 v = src[(size_t)r * 16 + l16];
            ACC4(v, 1.0f)
        }
    }
    if (cnt > 8) {
        int c16 = cnt < 16 ? cnt : 16;
        for (int j = 8; j < c16; ++j) {
            int r = __shfl(idx0, gbase + j, 64);
            uint2 v = src[(size_t)r * 16 + l16];
            ACC4(v, 1.0f)
        }
        for (int j = 16; j < cnt; ++j) {
            int r = csr_src[node * KMAX + j];
            uint2 v = src[(size_t)r * 16 + l16];
            ACC4(v, 1.0f)
        }
    }
    float4 bb = ((const float4*)bias)[l16];
    float h0 = fmaxf(fmaf(dn, a0, bb.x), 0.f);
    float h1 = fmaxf(fmaf(dn, a1, bb.y), 0.f);
    float h2 = fmaxf(fmaf(dn, a2, bb.z), 0.f);
    float h3 = fmaxf(fmaf(dn, a3, bb.w), 0.f);
    float4 ww = ((const float4*)W3)[l16];
    float v = h0 * ww.x + h1 * ww.y + h2 * ww.z + h3 * ww.w;
    v += __shfl_xor(v, 1, 64);
    v += __shfl_xor(v, 2, 64);
    v += __shfl_xor(v, 4, 64);
    v += __shfl_xor(v, 8, 64);                  // reduce within the 16-lane group
    if (l16 == 0) outp[g15 * 12 + (jj15 - 3)] = v + b3[0];
}

extern "C" void kernel_launch(void* const* d_in, const int* in_sizes, int n_in,
                              void* d_out, int out_size, void* d_ws, size_t ws_size,
                              hipStream_t stream) {
    const float* obs = (const float*)d_in[0];
    const int*   ei  = (const int*)d_in[1];
    const float* W1  = (const float*)d_in[2];
    const float* b1  = (const float*)d_in[3];
    const float* W2  = (const float*)d_in[4];
    const float* b2  = (const float*)d_in[5];
    const float* W3  = (const float*)d_in[6];
    const float* b3  = (const float*)d_in[7];
    float* out = (float*)d_out;

    char* ws = (char*)d_ws;
    size_t off = 0;
    auto alloc = [&](size_t bytes) -> void* {
        void* p = ws + off;
        off += (bytes + 255) & ~(size_t)255;
        return p;
    };
    int*   gcnt    = (int*)  alloc((size_t)NBUCK * 8 * 4);
    int*   cursor  = (int*)  alloc((size_t)NN * 4);
    float* dinvf   = (float*)alloc((size_t)NN * 4);
    int*   csr_src = (int*)  alloc((size_t)NN * KMAX * 4);          // 19.2 MB
    int2*  ebuf    = (int2*) alloc((size_t)NBUCK * 8 * SUBCAP * 8); // 7.2 MB
    unsigned short* XB  = (unsigned short*)alloc((size_t)NN * HID * 2);
    unsigned short* XB2 = (unsigned short*)alloc((size_t)NN * HID * 2);
    unsigned short* W1b = (unsigned short*)alloc((size_t)HID * IND * 2);
    unsigned short* W2b = (unsigned short*)alloc((size_t)HID * HID * 2);

    const int* rowv = ei;
    const int* colv = ei + NE;

    hipMemsetAsync(gcnt, 0, (size_t)NBUCK * 8 * 4, stream);
    k_init<<<PARTB + CVTB, 256, 0, stream>>>(rowv, colv, gcnt, ebuf, W1, W2, W1b, W2b);
    k_sort_gemm1<<<NBUCK + GEMM_GRID, 256, 0, stream>>>(obs, W1b, XB, gcnt, ebuf,
                                                        cursor, dinvf, csr_src);
    k_agg_gemm<<<GEMM_GRID, 256, 0, stream>>>(XB, cursor, dinvf, csr_src, b1, W2b, XB2);
    k_agg_out<<<(NN + 15) / 16, 256, 0, stream>>>(XB2, cursor, csr_src, b2, W3, b3, out);
}

// Round 15
// 110.503 us; speedup vs baseline: 1.1358x; 1.0390x over previous
//
#include <hip/hip_runtime.h>

#define NN 150000
#define NE 600000
#define IND 128
#define HID 64
#define KMAX 32            // CSR bucket stride; in-deg ~Poisson(4), P(>32) ~ 1e-19
#define BSHIFT 9
#define NBUCK 293          // ceil(NN / 512)
#define SUBCAP 384         // per-(bucket,xcd) edge cap; mean 256, +8 sigma
#define PARTB 586          // ceil(NE/4 / 256) partition blocks
#define CVTB 32            // W-convert blocks
#define GEMM_GRID ((NN + 63) / 64)       // 2344
#define NOUT 120000

typedef short s16x8 __attribute__((ext_vector_type(8)));
typedef float f32x4 __attribute__((ext_vector_type(4)));

__device__ __forceinline__ unsigned f2bf(float f) {
    unsigned u = __float_as_uint(f);
    return (u + 0x7FFFu + ((u >> 16) & 1u)) >> 16;   // RNE
}

#define ACC4(v, dr) \
    a0 = fmaf(__uint_as_float((v).x << 16), dr, a0); \
    a1 = fmaf(__uint_as_float((v).x & 0xFFFF0000u), dr, a1); \
    a2 = fmaf(__uint_as_float((v).y << 16), dr, a2); \
    a3 = fmaf(__uint_as_float((v).y & 0xFFFF0000u), dr, a3);

// ---------------- zero gcnt (replaces rocclr fillBuffer: 44us anomaly test) ----------------
__global__ void k_zero(int* __restrict__ gcnt) {
    int t = blockIdx.x * 256 + threadIdx.x;
    if (t < NBUCK * 8) gcnt[t] = 0;
}

// ---------------- hetero init: edge partition (Phase A) + W->bf16 ----------------
__global__ __launch_bounds__(256) void k_init(
        const int* __restrict__ rowv, const int* __restrict__ colv,
        int* __restrict__ gcnt, int2* __restrict__ ebuf,
        const float* __restrict__ W1, const float* __restrict__ W2,
        unsigned short* __restrict__ W1b, unsigned short* __restrict__ W2b) {
    int tid = threadIdx.x;
    if (blockIdx.x < PARTB) {
        __shared__ int hist[NBUCK];
        __shared__ int bases[NBUCK];
        for (int i = tid; i < NBUCK; i += 256) hist[i] = 0;
        __syncthreads();
        int t = blockIdx.x * 256 + tid;
        bool valid = (t < NE / 4);
        int4 r4, c4;
        int bk[4], sl[4];
        if (valid) {
            r4 = ((const int4*)rowv)[t];
            c4 = ((const int4*)colv)[t];
            bk[0] = c4.x >> BSHIFT; sl[0] = atomicAdd(&hist[bk[0]], 1);
            bk[1] = c4.y >> BSHIFT; sl[1] = atomicAdd(&hist[bk[1]], 1);
            bk[2] = c4.z >> BSHIFT; sl[2] = atomicAdd(&hist[bk[2]], 1);
            bk[3] = c4.w >> BSHIFT; sl[3] = atomicAdd(&hist[bk[3]], 1);
        }
        __syncthreads();
        int xcd = blockIdx.x & 7;
        for (int i = tid; i < NBUCK; i += 256)
            bases[i] = hist[i] ? atomicAdd(&gcnt[i * 8 + xcd], hist[i]) : 0;
        __syncthreads();
        if (valid) {
            #pragma unroll
            for (int e = 0; e < 4; ++e) {
                int c = (e == 0) ? c4.x : (e == 1) ? c4.y : (e == 2) ? c4.z : c4.w;
                int r = (e == 0) ? r4.x : (e == 1) ? r4.y : (e == 2) ? r4.z : r4.w;
                int p = bases[bk[e]] + sl[e];
                if (p < SUBCAP) ebuf[(bk[e] * 8 + xcd) * SUBCAP + p] = make_int2(c, r);
            }
        }
        return;
    }
    int t = (blockIdx.x - PARTB) * 256 + tid;
    if (t < HID * IND) W1b[t] = (unsigned short)f2bf(W1[t]);
    if (t < HID * HID) W2b[t] = (unsigned short)f2bf(W2[t]);
}

// ---------------- hetero: Phase-B bucket sort (LDS cursors) + gemm1 ----------------
__global__ __launch_bounds__(256) void k_sort_gemm1(
        const float* __restrict__ obs, const unsigned short* __restrict__ W1b,
        unsigned short* __restrict__ xs,
        const int* __restrict__ gcnt, const int2* __restrict__ ebuf,
        int* __restrict__ cursor, float* __restrict__ dinvf,
        int* __restrict__ csr_src) {
    __shared__ char smem[64 * IND * 2];         // gemm: W1 tile; sort: LDS cursors
    int tid = threadIdx.x;
    if (blockIdx.x < NBUCK) {
        int k = blockIdx.x;
        int lo = k << BSHIFT;
        int* cnt = (int*)smem;
        for (int i = tid; i < 512; i += 256) cnt[i] = 0;
        __syncthreads();
        for (int x = 0; x < 8; ++x) {
            int len = gcnt[k * 8 + x]; if (len > SUBCAP) len = SUBCAP;
            const int2* run = ebuf + (size_t)(k * 8 + x) * SUBCAP;
            for (int i = tid; i < len; i += 256) {
                int2 e = run[i];
                int s = atomicAdd(&cnt[e.x - lo], 1);       // LDS atomic
                if (s < KMAX) csr_src[e.x * KMAX + s] = e.y;
            }
        }
        __syncthreads();
        for (int i = tid; i < 512; i += 256) {
            int n = lo + i;
            if (n < NN) {
                cursor[n] = cnt[i];
                dinvf[n] = rsqrtf((float)(cnt[i] + 1));
            }
        }
        return;
    }
    char* sB = smem;
    int base = (blockIdx.x - NBUCK) * 64;

    {
        const uint4* Wsrc = (const uint4*)W1b;  // 8 bf16 per uint4
        for (int idx = tid; idx < 8 * IND; idx += 256) {
            int row = idx >> 4, c8 = idx & 15;
            uint4 v = Wsrc[idx];
            int byte = row * (IND * 2) + c8 * 16;
            byte ^= (row & 7) << 4;
            *(uint4*)(sB + byte) = v;
        }
    }
    __syncthreads();

    int wave = tid >> 6, lane = tid & 63;
    int r16 = lane & 15, kg = lane >> 4;
    int arow = base + 16 * wave + r16;
    if (arow >= NN) arow = NN - 1;
    const float4* Ap = (const float4*)(obs + (size_t)arow * IND) + kg * 2;

    float4 va[8];
    #pragma unroll
    for (int s = 0; s < 4; ++s) {
        va[2 * s]     = Ap[s * 8];
        va[2 * s + 1] = Ap[s * 8 + 1];
    }

    f32x4 acc[4];
    #pragma unroll
    for (int j = 0; j < 4; ++j) acc[j] = (f32x4){0.f, 0.f, 0.f, 0.f};

    #pragma unroll
    for (int s = 0; s < 4; ++s) {
        float4 v0 = va[2 * s], v1 = va[2 * s + 1];
        s16x8 a;
        a[0] = (short)f2bf(v0.x); a[1] = (short)f2bf(v0.y);
        a[2] = (short)f2bf(v0.z); a[3] = (short)f2bf(v0.w);
        a[4] = (short)f2bf(v1.x); a[5] = (short)f2bf(v1.y);
        a[6] = (short)f2bf(v1.z); a[7] = (short)f2bf(v1.w);
        int kb = (s * 32 + kg * 8) * 2;
        #pragma unroll
        for (int j = 0; j < 4; ++j) {
            int row = 16 * j + r16;
            int byte = row * (IND * 2) + kb;
            byte ^= (row & 7) << 4;
            s16x8 b = *(const s16x8*)(sB + byte);
            acc[j] = __builtin_amdgcn_mfma_f32_16x16x32_bf16(a, b, acc[j], 0, 0, 0);
        }
    }

    #pragma unroll
    for (int r = 0; r < 4; ++r) {
        int n = base + 16 * wave + kg * 4 + r;
        if (n >= NN) continue;
        #pragma unroll
        for (int j = 0; j < 4; ++j) {
            int c = 16 * j + r16;
            xs[(size_t)n * HID + c] = (unsigned short)f2bf(acc[j][r]);
        }
    }
}

// ---------------- fused agg1 + gemm2 (MLP-first gather) ----------------
__global__ __launch_bounds__(256) void k_agg_gemm(
        const unsigned short* __restrict__ xs, const int* __restrict__ cursor,
        const float* __restrict__ dinvf, const int* __restrict__ csr_src,
        const float* __restrict__ bias, const unsigned short* __restrict__ W2b,
        unsigned short* __restrict__ xs2) {
    __shared__ char smem[2 * 64 * HID * 2];
    char* sA = smem;
    char* sB = smem + 64 * HID * 2;
    int tid = threadIdx.x;
    int base = blockIdx.x * 64;

    {
        const uint4* Wsrc = (const uint4*)W2b;
        for (int idx = tid; idx < 8 * HID; idx += 256) {
            int row = idx >> 3, c8 = idx & 7;
            uint4 v = Wsrc[idx];
            int byte = row * (HID * 2) + c8 * 16;
            byte ^= (row & 7) << 4;
            *(uint4*)(sB + byte) = v;
        }
    }

    int lane = tid & 63;
    int l16 = lane & 15, gbase = lane & 48;
    int grp = tid >> 4;
    const uint2* src = (const uint2*)xs;
    float4 bb = ((const float4*)bias)[l16];

    int degA[4], cntA[4], idxA[4];
    uint2 svA[4];
    float drA[4];
    #pragma unroll
    for (int s4 = 0; s4 < 4; ++s4) {
        int node = base + s4 * 16 + grp;
        bool ok = node < NN;
        int nc = ok ? node : NN - 1;
        int deg = cursor[nc];
        degA[s4] = deg;
        cntA[s4] = ok ? (deg < KMAX ? deg : KMAX) : 0;
        idxA[s4] = csr_src[nc * KMAX + l16];    // 64B/group: slots 0..15
        svA[s4]  = src[(size_t)nc * 16 + l16];  // self row
    }
    #pragma unroll
    for (int s4 = 0; s4 < 4; ++s4) {
        int safe = (l16 < cntA[s4]) ? idxA[s4] : 0;
        drA[s4] = dinvf[safe];                  // dr for this lane's slot
    }

    #pragma unroll
    for (int s4 = 0; s4 < 4; ++s4) {
        int row = s4 * 16 + grp;
        int node = base + row;
        int cnt = cntA[s4];
        float dn = rsqrtf((float)(degA[s4] + 1));
        uint2 sv = svA[s4];
        float a0 = __uint_as_float(sv.x << 16) * dn;
        float a1 = __uint_as_float(sv.x & 0xFFFF0000u) * dn;
        float a2 = __uint_as_float(sv.y << 16) * dn;
        float a3 = __uint_as_float(sv.y & 0xFFFF0000u) * dn;
        #pragma unroll
        for (int j = 0; j < 8; ++j) {
            int r    = __shfl(idxA[s4], gbase + j, 64);
            float dr = __shfl(drA[s4], gbase + j, 64);
            if (j < cnt) {
                uint2 v = src[(size_t)r * 16 + l16];
                ACC4(v, dr)
            }
        }
        if (cnt > 8) {
            int c16 = cnt < 16 ? cnt : 16;
            for (int j = 8; j < c16; ++j) {
                int r    = __shfl(idxA[s4], gbase + j, 64);
                float dr = __shfl(drA[s4], gbase + j, 64);
                uint2 v = src[(size_t)r * 16 + l16];
                ACC4(v, dr)
            }
            for (int j = 16; j < cnt; ++j) {    // ultra-rare
                int r = csr_src[node * KMAX + j];
                float dr = dinvf[r];
                uint2 v = src[(size_t)r * 16 + l16];
                ACC4(v, dr)
            }
        }
        float h0 = fmaxf(fmaf(dn, a0, bb.x), 0.f);
        float h1 = fmaxf(fmaf(dn, a1, bb.y), 0.f);
        float h2 = fmaxf(fmaf(dn, a2, bb.z), 0.f);
        float h3 = fmaxf(fmaf(dn, a3, bb.w), 0.f);
        uint2 o;
        o.x = f2bf(h0) | (f2bf(h1) << 16);
        o.y = f2bf(h2) | (f2bf(h3) << 16);
        if (node >= NN) { o.x = 0u; o.y = 0u; }
        int byte = row * (HID * 2) + l16 * 8;
        byte ^= (row & 7) << 4;
        *(uint2*)(sA + byte) = o;
    }
    __syncthreads();

    int wave = tid >> 6;
    int wr = wave >> 1, wc = wave & 1;
    int r16 = lane & 15, kg = lane >> 4;

    f32x4 acc[2][2];
    #pragma unroll
    for (int i = 0; i < 2; ++i)
        #pragma unroll
        for (int j = 0; j < 2; ++j)
            acc[i][j] = (f32x4){0.f, 0.f, 0.f, 0.f};

    #pragma unroll
    for (int s = 0; s < HID / 32; ++s) {
        int kb = (s * 32 + kg * 8) * 2;
        s16x8 a[2], b[2];
        #pragma unroll
        for (int i = 0; i < 2; ++i) {
            int row = 32 * wr + 16 * i + r16;
            int byte = row * (HID * 2) + kb;
            byte ^= (row & 7) << 4;
            a[i] = *(const s16x8*)(sA + byte);
        }
        #pragma unroll
        for (int j = 0; j < 2; ++j) {
            int row = 32 * wc + 16 * j + r16;
            int byte = row * (HID * 2) + kb;
            byte ^= (row & 7) << 4;
            b[j] = *(const s16x8*)(sB + byte);
        }
        #pragma unroll
        for (int i = 0; i < 2; ++i)
            #pragma unroll
            for (int j = 0; j < 2; ++j)
                acc[i][j] = __builtin_amdgcn_mfma_f32_16x16x32_bf16(a[i], b[j], acc[i][j], 0, 0, 0);
    }

    #pragma unroll
    for (int i = 0; i < 2; ++i) {
        #pragma unroll
        for (int r = 0; r < 4; ++r) {
            int n = base + 32 * wr + 16 * i + kg * 4 + r;
            if (n >= NN) continue;
            float d = dinvf[n];                 // pre-scale layer-2 source side
            #pragma unroll
            for (int j = 0; j < 2; ++j) {
                int c = 32 * wc + 16 * j + r16;
                xs2[(size_t)n * HID + c] = (unsigned short)f2bf(acc[i][j][r] * d);
            }
        }
    }
}

// ---------------- agg2 + final dot (needed nodes only: q in [0,120000)) ----------------
__global__ __launch_bounds__(256) void k_agg_out(const unsigned short* __restrict__ xs,
                      const int* __restrict__ cursor, const int* __restrict__ csr_src,
                      const float* __restrict__ bias, const float* __restrict__ W3,
                      const float* __restrict__ b3, float* __restrict__ outp) {
    int tid = threadIdx.x;
    int lane = tid & 63;
    int l16 = lane & 15, gbase = lane & 48;
    int q = blockIdx.x * 16 + (tid >> 4);
    if (q >= NOUT) return;
    int g15 = q / 12, jj12 = q - g15 * 12;
    int node = g15 * 15 + 3 + jj12;
    int deg = cursor[node];
    int cnt = deg < KMAX ? deg : KMAX;
    float dn = rsqrtf((float)(deg + 1));
    const uint2* src = (const uint2*)xs;
    int idx0 = csr_src[node * KMAX + l16];      // 64B: slots 0..15
    uint2 sv = src[(size_t)node * 16 + l16];
    float a0 = __uint_as_float(sv.x << 16);
    float a1 = __uint_as_float(sv.x & 0xFFFF0000u);
    float a2 = __uint_as_float(sv.y << 16);
    float a3 = __uint_as_float(sv.y & 0xFFFF0000u);
    #pragma unroll
    for (int j = 0; j < 8; ++j) {
        int r = __shfl(idx0, gbase + j, 64);
        if (j < cnt) {
            uint2 v = src[(size_t)r * 16 + l16];
            ACC4(v, 1.0f)
        }
    }
    if (cnt > 8) {
        int c16 = cnt < 16 ? cnt : 16;
        for (int j = 8; j < c16; ++j) {
            int r = __shfl(idx0, gbase + j, 64);
            uint2 v = src[(size_t)r * 16 + l16];
            ACC4(v, 1.0f)
        }
        for (int j = 16; j < cnt; ++j) {
            int r = csr_src[node * KMAX + j];
            uint2 v = src[(size_t)r * 16 + l16];
            ACC4(v, 1.0f)
        }
    }
    float4 bb = ((const float4*)bias)[l16];
    float h0 = fmaxf(fmaf(dn, a0, bb.x), 0.f);
    float h1 = fmaxf(fmaf(dn, a1, bb.y), 0.f);
    float h2 = fmaxf(fmaf(dn, a2, bb.z), 0.f);
    float h3 = fmaxf(fmaf(dn, a3, bb.w), 0.f);
    float4 ww = ((const float4*)W3)[l16];
    float v = h0 * ww.x + h1 * ww.y + h2 * ww.z + h3 * ww.w;
    v += __shfl_xor(v, 1, 64);
    v += __shfl_xor(v, 2, 64);
    v += __shfl_xor(v, 4, 64);
    v += __shfl_xor(v, 8, 64);                  // reduce within the 16-lane group
    if (l16 == 0) outp[q] = v + b3[0];
}

extern "C" void kernel_launch(void* const* d_in, const int* in_sizes, int n_in,
                              void* d_out, int out_size, void* d_ws, size_t ws_size,
                              hipStream_t stream) {
    const float* obs = (const float*)d_in[0];
    const int*   ei  = (const int*)d_in[1];
    const float* W1  = (const float*)d_in[2];
    const float* b1  = (const float*)d_in[3];
    const float* W2  = (const float*)d_in[4];
    const float* b2  = (const float*)d_in[5];
    const float* W3  = (const float*)d_in[6];
    const float* b3  = (const float*)d_in[7];
    float* out = (float*)d_out;

    char* ws = (char*)d_ws;
    size_t off = 0;
    auto alloc = [&](size_t bytes) -> void* {
        void* p = ws + off;
        off += (bytes + 255) & ~(size_t)255;
        return p;
    };
    int*   gcnt    = (int*)  alloc((size_t)NBUCK * 8 * 4);
    int*   cursor  = (int*)  alloc((size_t)NN * 4);
    float* dinvf   = (float*)alloc((size_t)NN * 4);
    int*   csr_src = (int*)  alloc((size_t)NN * KMAX * 4);          // 19.2 MB
    int2*  ebuf    = (int2*) alloc((size_t)NBUCK * 8 * SUBCAP * 8); // 7.2 MB
    unsigned short* XB  = (unsigned short*)alloc((size_t)NN * HID * 2);
    unsigned short* XB2 = (unsigned short*)alloc((size_t)NN * HID * 2);
    unsigned short* W1b = (unsigned short*)alloc((size_t)HID * IND * 2);
    unsigned short* W2b = (unsigned short*)alloc((size_t)HID * HID * 2);

    const int* rowv = ei;
    const int* colv = ei + NE;

    k_zero<<<(NBUCK * 8 + 255) / 256, 256, 0, stream>>>(gcnt);
    k_init<<<PARTB + CVTB, 256, 0, stream>>>(rowv, colv, gcnt, ebuf, W1, W2, W1b, W2b);
    k_sort_gemm1<<<NBUCK + GEMM_GRID, 256, 0, stream>>>(obs, W1b, XB, gcnt, ebuf,
                                                        cursor, dinvf, csr_src);
    k_agg_gemm<<<GEMM_GRID, 256, 0, stream>>>(XB, cursor, dinvf, csr_src, b1, W2b, XB2);
    k_agg_out<<<(NOUT + 15) / 16, 256, 0, stream>>>(XB2, cursor, csr_src, b2, W3, b3, out);
}

// Round 16
// 107.769 us; speedup vs baseline: 1.1646x; 1.0254x over previous
//
#include <hip/hip_runtime.h>

#define NN 150000
#define NE 600000
#define IND 128
#define HID 64
#define KMAX 32            // CSR bucket stride; in-deg ~Poisson(4), P(>32) ~ 1e-19
#define BSHIFT 8
#define NBUCK 586          // ceil(NN / 256)
#define SUBCAP 224         // per-(bucket,xcd) edge cap; mean 128, +8.5 sigma
#define PARTB 586          // ceil(NE/4 / 256) partition blocks
#define GEMM_GRID ((NN + 63) / 64)       // 2344
#define NOUT 120000

typedef short s16x8 __attribute__((ext_vector_type(8)));
typedef float f32x4 __attribute__((ext_vector_type(4)));

__device__ __forceinline__ unsigned f2bf(float f) {
    unsigned u = __float_as_uint(f);
    return (u + 0x7FFFu + ((u >> 16) & 1u)) >> 16;   // RNE
}

#define ACC4(v, dr) \
    a0 = fmaf(__uint_as_float((v).x << 16), dr, a0); \
    a1 = fmaf(__uint_as_float((v).x & 0xFFFF0000u), dr, a1); \
    a2 = fmaf(__uint_as_float((v).y << 16), dr, a2); \
    a3 = fmaf(__uint_as_float((v).y & 0xFFFF0000u), dr, a3);

// ---------------- zero gcnt ----------------
__global__ void k_zero(int* __restrict__ gcnt) {
    int t = blockIdx.x * 256 + threadIdx.x;
    if (t < NBUCK * 8) gcnt[t] = 0;
}

// ---------------- hetero: edge partition + gemm1 ----------------
// Partition blocks (first PARTB): stream edge quads once; LDS-histogram by dst
// bucket (dst>>8); one reservation atomic per non-empty bucket per block; write
// (dst,src) runs into per-(bucket,xcd) sub-windows. No per-edge global atomics.
// gemm1 blocks: xs[n][c] = bf16( sum_k obs[n][k]*W1[c][k] ) UNSCALED (dinv on
// gather). W1 converted fp32->bf16 during LDS staging (no W1b buffer). wave =
// 16 rows x 64 cols; A direct from global; W1 LDS XOR-swizzled (byte^=(row&7)<<4).
__global__ __launch_bounds__(256) void k_init(
        const int* __restrict__ rowv, const int* __restrict__ colv,
        int* __restrict__ gcnt, int2* __restrict__ ebuf,
        const float* __restrict__ obs, const float* __restrict__ W1,
        unsigned short* __restrict__ xs) {
    __shared__ char smem[64 * IND * 2];         // 16 KB; partition aliases hist/bases
    int tid = threadIdx.x;
    if (blockIdx.x < PARTB) {
        int* hist  = (int*)smem;
        int* bases = hist + NBUCK;
        for (int i = tid; i < NBUCK; i += 256) hist[i] = 0;
        __syncthreads();
        int t = blockIdx.x * 256 + tid;
        bool valid = (t < NE / 4);
        int4 r4, c4;
        int bk[4], sl[4];
        if (valid) {
            r4 = ((const int4*)rowv)[t];
            c4 = ((const int4*)colv)[t];
            bk[0] = c4.x >> BSHIFT; sl[0] = atomicAdd(&hist[bk[0]], 1);
            bk[1] = c4.y >> BSHIFT; sl[1] = atomicAdd(&hist[bk[1]], 1);
            bk[2] = c4.z >> BSHIFT; sl[2] = atomicAdd(&hist[bk[2]], 1);
            bk[3] = c4.w >> BSHIFT; sl[3] = atomicAdd(&hist[bk[3]], 1);
        }
        __syncthreads();
        int xcd = blockIdx.x & 7;
        for (int i = tid; i < NBUCK; i += 256)
            bases[i] = hist[i] ? atomicAdd(&gcnt[i * 8 + xcd], hist[i]) : 0;
        __syncthreads();
        if (valid) {
            #pragma unroll
            for (int e = 0; e < 4; ++e) {
                int c = (e == 0) ? c4.x : (e == 1) ? c4.y : (e == 2) ? c4.z : c4.w;
                int r = (e == 0) ? r4.x : (e == 1) ? r4.y : (e == 2) ? r4.z : r4.w;
                int p = bases[bk[e]] + sl[e];
                if (p < SUBCAP) ebuf[(bk[e] * 8 + xcd) * SUBCAP + p] = make_int2(c, r);
            }
        }
        return;
    }
    char* sB = smem;
    int base = (blockIdx.x - PARTB) * 64;

    {   // stage W1 fp32 -> bf16 swizzled (64 rows x 32 float4)
        const float4* Wsrc = (const float4*)W1;
        for (int idx = tid; idx < 64 * 32; idx += 256) {
            int row = idx >> 5, c4i = idx & 31;
            float4 w = Wsrc[idx];
            uint2 p;
            p.x = f2bf(w.x) | (f2bf(w.y) << 16);
            p.y = f2bf(w.z) | (f2bf(w.w) << 16);
            int byte = row * (IND * 2) + c4i * 8;
            byte ^= (row & 7) << 4;
            *(uint2*)(sB + byte) = p;
        }
    }
    __syncthreads();

    int wave = tid >> 6, lane = tid & 63;
    int r16 = lane & 15, kg = lane >> 4;
    int arow = base + 16 * wave + r16;
    if (arow >= NN) arow = NN - 1;
    const float4* Ap = (const float4*)(obs + (size_t)arow * IND) + kg * 2;

    float4 va[8];
    #pragma unroll
    for (int s = 0; s < 4; ++s) {
        va[2 * s]     = Ap[s * 8];
        va[2 * s + 1] = Ap[s * 8 + 1];
    }

    f32x4 acc[4];
    #pragma unroll
    for (int j = 0; j < 4; ++j) acc[j] = (f32x4){0.f, 0.f, 0.f, 0.f};

    #pragma unroll
    for (int s = 0; s < 4; ++s) {
        float4 v0 = va[2 * s], v1 = va[2 * s + 1];
        s16x8 a;
        a[0] = (short)f2bf(v0.x); a[1] = (short)f2bf(v0.y);
        a[2] = (short)f2bf(v0.z); a[3] = (short)f2bf(v0.w);
        a[4] = (short)f2bf(v1.x); a[5] = (short)f2bf(v1.y);
        a[6] = (short)f2bf(v1.z); a[7] = (short)f2bf(v1.w);
        int kb = (s * 32 + kg * 8) * 2;
        #pragma unroll
        for (int j = 0; j < 4; ++j) {
            int row = 16 * j + r16;
            int byte = row * (IND * 2) + kb;
            byte ^= (row & 7) << 4;
            s16x8 b = *(const s16x8*)(sB + byte);
            acc[j] = __builtin_amdgcn_mfma_f32_16x16x32_bf16(a, b, acc[j], 0, 0, 0);
        }
    }

    #pragma unroll
    for (int r = 0; r < 4; ++r) {
        int n = base + 16 * wave + kg * 4 + r;
        if (n >= NN) continue;
        #pragma unroll
        for (int j = 0; j < 4; ++j) {
            int c = 16 * j + r16;
            xs[(size_t)n * HID + c] = (unsigned short)f2bf(acc[j][r]);
        }
    }
}

// ---------------- bucket sort: block owns 256 nodes exclusively ----------------
__global__ __launch_bounds__(256) void k_sort(
        const int* __restrict__ gcnt, const int2* __restrict__ ebuf,
        int* __restrict__ cursor, float* __restrict__ dinvf,
        int* __restrict__ csr_src) {
    __shared__ int cnt[256];
    int tid = threadIdx.x;
    int k = blockIdx.x;
    int lo = k << BSHIFT;
    cnt[tid] = 0;
    __syncthreads();
    for (int x = 0; x < 8; ++x) {
        int len = gcnt[k * 8 + x]; if (len > SUBCAP) len = SUBCAP;
        const int2* run = ebuf + (size_t)(k * 8 + x) * SUBCAP;
        for (int i = tid; i < len; i += 256) {
            int2 e = run[i];
            int s = atomicAdd(&cnt[e.x - lo], 1);       // LDS atomic
            if (s < KMAX) csr_src[e.x * KMAX + s] = e.y;
        }
    }
    __syncthreads();
    int n = lo + tid;
    if (n < NN) {
        cursor[n] = cnt[tid];
        dinvf[n] = rsqrtf((float)(cnt[tid] + 1));
    }
}

// ---------------- fused agg1 + gemm2 (branch-free batched gathers) ----------------
__global__ __launch_bounds__(256) void k_agg_gemm(
        const unsigned short* __restrict__ xs, const int* __restrict__ cursor,
        const float* __restrict__ dinvf, const int* __restrict__ csr_src,
        const float* __restrict__ bias, const float* __restrict__ W2,
        unsigned short* __restrict__ xs2) {
    __shared__ char smem[2 * 64 * HID * 2];
    char* sA = smem;
    char* sB = smem + 64 * HID * 2;
    int tid = threadIdx.x;
    int base = blockIdx.x * 64;

    {   // stage W2 fp32 -> bf16 swizzled (64 rows x 16 float4)
        const float4* Wsrc = (const float4*)W2;
        for (int idx = tid; idx < 64 * 16; idx += 256) {
            int row = idx >> 4, c4i = idx & 15;
            float4 w = Wsrc[idx];
            uint2 p;
            p.x = f2bf(w.x) | (f2bf(w.y) << 16);
            p.y = f2bf(w.z) | (f2bf(w.w) << 16);
            int byte = row * (HID * 2) + c4i * 8;
            byte ^= (row & 7) << 4;
            *(uint2*)(sB + byte) = p;
        }
    }

    int lane = tid & 63;
    int l16 = lane & 15, gbase = lane & 48;
    int grp = tid >> 4;
    const uint2* src = (const uint2*)xs;
    float4 bb = ((const float4*)bias)[l16];

    int degA[4], cntA[4], idxA[4];
    uint2 svA[4];
    float drA[4];
    #pragma unroll
    for (int s4 = 0; s4 < 4; ++s4) {
        int node = base + s4 * 16 + grp;
        bool ok = node < NN;
        int nc = ok ? node : NN - 1;
        int deg = cursor[nc];
        degA[s4] = deg;
        cntA[s4] = ok ? (deg < KMAX ? deg : KMAX) : 0;
        idxA[s4] = csr_src[nc * KMAX + l16];    // 64B/group: slots 0..15
        svA[s4]  = src[(size_t)nc * 16 + l16];  // self row
    }
    #pragma unroll
    for (int s4 = 0; s4 < 4; ++s4) {
        // weight for this lane's slot: 0 if slot invalid -> branch-free inner loop
        drA[s4] = (l16 < cntA[s4]) ? dinvf[idxA[s4]] : 0.0f;
    }

    #pragma unroll
    for (int s4 = 0; s4 < 4; ++s4) {
        int row = s4 * 16 + grp;
        int node = base + row;
        int cnt = cntA[s4];
        float dn = rsqrtf((float)(degA[s4] + 1));
        uint2 sv = svA[s4];
        float a0 = __uint_as_float(sv.x << 16) * dn;
        float a1 = __uint_as_float(sv.x & 0xFFFF0000u) * dn;
        float a2 = __uint_as_float(sv.y << 16) * dn;
        float a3 = __uint_as_float(sv.y & 0xFFFF0000u) * dn;
        // batch: 8 unconditional gathers (invalid -> row 0, hot L2 line), then consume
        uint2 v[8];
        #pragma unroll
        for (int j = 0; j < 8; ++j) {
            int r = __shfl(idxA[s4], gbase + j, 64);
            r = (j < cnt) ? r : 0;
            v[j] = src[(size_t)r * 16 + l16];
        }
        #pragma unroll
        for (int j = 0; j < 8; ++j) {
            float dr = __shfl(drA[s4], gbase + j, 64);  // 0 for invalid slots
            ACC4(v[j], dr)
        }
        if (cnt > 8) {
            int c16 = cnt < 16 ? cnt : 16;
            for (int j = 8; j < c16; ++j) {
                int r    = __shfl(idxA[s4], gbase + j, 64);
                float dr = __shfl(drA[s4], gbase + j, 64);
                uint2 vv = src[(size_t)r * 16 + l16];
                ACC4(vv, dr)
            }
            for (int j = 16; j < cnt; ++j) {    // ultra-rare
                int r = csr_src[node * KMAX + j];
                float dr = dinvf[r];
                uint2 vv = src[(size_t)r * 16 + l16];
                ACC4(vv, dr)
            }
        }
        float h0 = fmaxf(fmaf(dn, a0, bb.x), 0.f);
        float h1 = fmaxf(fmaf(dn, a1, bb.y), 0.f);
        float h2 = fmaxf(fmaf(dn, a2, bb.z), 0.f);
        float h3 = fmaxf(fmaf(dn, a3, bb.w), 0.f);
        uint2 o;
        o.x = f2bf(h0) | (f2bf(h1) << 16);
        o.y = f2bf(h2) | (f2bf(h3) << 16);
        if (node >= NN) { o.x = 0u; o.y = 0u; }
        int byte = row * (HID * 2) + l16 * 8;
        byte ^= (row & 7) << 4;
        *(uint2*)(sA + byte) = o;
    }
    __syncthreads();

    int wave = tid >> 6;
    int wr = wave >> 1, wc = wave & 1;
    int r16 = lane & 15, kg = lane >> 4;

    f32x4 acc[2][2];
    #pragma unroll
    for (int i = 0; i < 2; ++i)
        #pragma unroll
        for (int j = 0; j < 2; ++j)
            acc[i][j] = (f32x4){0.f, 0.f, 0.f, 0.f};

    #pragma unroll
    for (int s = 0; s < HID / 32; ++s) {
        int kb = (s * 32 + kg * 8) * 2;
        s16x8 a[2], b[2];
        #pragma unroll
        for (int i = 0; i < 2; ++i) {
            int row = 32 * wr + 16 * i + r16;
            int byte = row * (HID * 2) + kb;
            byte ^= (row & 7) << 4;
            a[i] = *(const s16x8*)(sA + byte);
        }
        #pragma unroll
        for (int j = 0; j < 2; ++j) {
            int row = 32 * wc + 16 * j + r16;
            int byte = row * (HID * 2) + kb;
            byte ^= (row & 7) << 4;
            b[j] = *(const s16x8*)(sB + byte);
        }
        #pragma unroll
        for (int i = 0; i < 2; ++i)
            #pragma unroll
            for (int j = 0; j < 2; ++j)
                acc[i][j] = __builtin_amdgcn_mfma_f32_16x16x32_bf16(a[i], b[j], acc[i][j], 0, 0, 0);
    }

    #pragma unroll
    for (int i = 0; i < 2; ++i) {
        #pragma unroll
        for (int r = 0; r < 4; ++r) {
            int n = base + 32 * wr + 16 * i + kg * 4 + r;
            if (n >= NN) continue;
            float d = dinvf[n];                 // pre-scale layer-2 source side
            #pragma unroll
            for (int j = 0; j < 2; ++j) {
                int c = 32 * wc + 16 * j + r16;
                xs2[(size_t)n * HID + c] = (unsigned short)f2bf(acc[i][j][r] * d);
            }
        }
    }
}

// ---------------- agg2 + final dot (needed nodes only; batched gathers) ----------------
__global__ __launch_bounds__(256) void k_agg_out(const unsigned short* __restrict__ xs,
                      const int* __restrict__ cursor, const int* __restrict__ csr_src,
                      const float* __restrict__ bias, const float* __restrict__ W3,
                      const float* __restrict__ b3, float* __restrict__ outp) {
    int tid = threadIdx.x;
    int lane = tid & 63;
    int l16 = lane & 15, gbase = lane & 48;
    int q = blockIdx.x * 16 + (tid >> 4);
    if (q >= NOUT) return;
    int g15 = q / 12, jj12 = q - g15 * 12;
    int node = g15 * 15 + 3 + jj12;
    int deg = cursor[node];
    int cnt = deg < KMAX ? deg : KMAX;
    float dn = rsqrtf((float)(deg + 1));
    const uint2* src = (const uint2*)xs;
    int idx0 = csr_src[node * KMAX + l16];      // 64B: slots 0..15
    float w0 = (l16 < cnt) ? 1.0f : 0.0f;       // slot validity weight
    uint2 sv = src[(size_t)node * 16 + l16];
    float a0 = __uint_as_float(sv.x << 16);
    float a1 = __uint_as_float(sv.x & 0xFFFF0000u);
    float a2 = __uint_as_float(sv.y << 16);
    float a3 = __uint_as_float(sv.y & 0xFFFF0000u);
    uint2 v[8];
    #pragma unroll
    for (int j = 0; j < 8; ++j) {
        int r = __shfl(idx0, gbase + j, 64);
        r = (j < cnt) ? r : 0;
        v[j] = src[(size_t)r * 16 + l16];
    }
    #pragma unroll
    for (int j = 0; j < 8; ++j) {
        float w = __shfl(w0, gbase + j, 64);
        ACC4(v[j], w)
    }
    if (cnt > 8) {
        int c16 = cnt < 16 ? cnt : 16;
        for (int j = 8; j < c16; ++j) {
            int r = __shfl(idx0, gbase + j, 64);
            uint2 vv = src[(size_t)r * 16 + l16];
            ACC4(vv, 1.0f)
        }
        for (int j = 16; j < cnt; ++j) {
            int r = csr_src[node * KMAX + j];
            uint2 vv = src[(size_t)r * 16 + l16];
            ACC4(vv, 1.0f)
        }
    }
    float4 bb = ((const float4*)bias)[l16];
    float h0 = fmaxf(fmaf(dn, a0, bb.x), 0.f);
    float h1 = fmaxf(fmaf(dn, a1, bb.y), 0.f);
    float h2 = fmaxf(fmaf(dn, a2, bb.z), 0.f);
    float h3 = fmaxf(fmaf(dn, a3, bb.w), 0.f);
    float4 ww = ((const float4*)W3)[l16];
    float v3 = h0 * ww.x + h1 * ww.y + h2 * ww.z + h3 * ww.w;
    v3 += __shfl_xor(v3, 1, 64);
    v3 += __shfl_xor(v3, 2, 64);
    v3 += __shfl_xor(v3, 4, 64);
    v3 += __shfl_xor(v3, 8, 64);                // reduce within the 16-lane group
    if (l16 == 0) outp[q] = v3 + b3[0];
}

extern "C" void kernel_launch(void* const* d_in, const int* in_sizes, int n_in,
                              void* d_out, int out_size, void* d_ws, size_t ws_size,
                              hipStream_t stream) {
    const float* obs = (const float*)d_in[0];
    const int*   ei  = (const int*)d_in[1];
    const float* W1  = (const float*)d_in[2];
    const float* b1  = (const float*)d_in[3];
    const float* W2  = (const float*)d_in[4];
    const float* b2  = (const float*)d_in[5];
    const float* W3  = (const float*)d_in[6];
    const float* b3  = (const float*)d_in[7];
    float* out = (float*)d_out;

    char* ws = (char*)d_ws;
    size_t off = 0;
    auto alloc = [&](size_t bytes) -> void* {
        void* p = ws + off;
        off += (bytes + 255) & ~(size_t)255;
        return p;
    };
    int*   gcnt    = (int*)  alloc((size_t)NBUCK * 8 * 4);          // 18.8 KB
    int*   cursor  = (int*)  alloc((size_t)NN * 4);
    float* dinvf   = (float*)alloc((size_t)NN * 4);
    int*   csr_src = (int*)  alloc((size_t)NN * KMAX * 4);          // 19.2 MB
    int2*  ebuf    = (int2*) alloc((size_t)NBUCK * 8 * SUBCAP * 8); // 8.4 MB
    unsigned short* XB  = (unsigned short*)alloc((size_t)NN * HID * 2);
    unsigned short* XB2 = (unsigned short*)alloc((size_t)NN * HID * 2);

    const int* rowv = ei;
    const int* colv = ei + NE;

    k_zero<<<(NBUCK * 8 + 255) / 256, 256, 0, stream>>>(gcnt);
    k_init<<<PARTB + GEMM_GRID, 256, 0, stream>>>(rowv, colv, gcnt, ebuf, obs, W1, XB);
    k_sort<<<NBUCK, 256, 0, stream>>>(gcnt, ebuf, cursor, dinvf, csr_src);
    k_agg_gemm<<<GEMM_GRID, 256, 0, stream>>>(XB, cursor, dinvf, csr_src, b1, W2, XB2);
    k_agg_out<<<(NOUT + 15) / 16, 256, 0, stream>>>(XB2, cursor, csr_src, b2, W3, b3, out);
}

// Round 17
// 95.526 us; speedup vs baseline: 1.3139x; 1.1282x over previous
//
#include <hip/hip_runtime.h>

#define NN 150000
#define NE 600000
#define IND 128
#define HID 64
#define KMAX 32            // CSR bucket stride; in-deg ~Poisson(4), P(>32) ~ 1e-19
#define BSHIFT 8
#define NBUCK 586          // ceil(NN / 256)
#define SUBCAP 224         // per-(bucket,xcd) edge cap; mean ~129, +8 sigma
#define PARTB 293          // partition blocks, 8 edges/thread (2 x int4)
#define GEMM_GRID ((NN + 63) / 64)       // 2344
#define NOUT 120000

typedef short s16x8 __attribute__((ext_vector_type(8)));
typedef float f32x4 __attribute__((ext_vector_type(4)));

__device__ __forceinline__ unsigned f2bf(float f) {
    unsigned u = __float_as_uint(f);
    return (u + 0x7FFFu + ((u >> 16) & 1u)) >> 16;   // RNE
}

#define ACC4(v, dr) \
    a0 = fmaf(__uint_as_float((v).x << 16), dr, a0); \
    a1 = fmaf(__uint_as_float((v).x & 0xFFFF0000u), dr, a1); \
    a2 = fmaf(__uint_as_float((v).y << 16), dr, a2); \
    a3 = fmaf(__uint_as_float((v).y & 0xFFFF0000u), dr, a3);

// ---------------- zero gcnt ----------------
__global__ void k_zero(int* __restrict__ gcnt) {
    int t = blockIdx.x * 256 + threadIdx.x;
    if (t < NBUCK * 8) gcnt[t] = 0;
}

// ---------------- edge partition: 8 edges/thread, LDS histogram ----------------
// Stream edge quads once; LDS-histogram by dst bucket (dst>>8); one reservation
// atomic per non-empty bucket per block; write (dst,src) runs into the block's
// per-(bucket,xcd) sub-window. No per-edge global atomics.
__global__ __launch_bounds__(256) void k_part(
        const int* __restrict__ rowv, const int* __restrict__ colv,
        int* __restrict__ gcnt, int2* __restrict__ ebuf) {
    __shared__ int hist[NBUCK];
    __shared__ int bases[NBUCK];
    int tid = threadIdx.x;
    for (int i = tid; i < NBUCK; i += 256) hist[i] = 0;
    __syncthreads();
    int4 r4[2], c4[2];
    int bk[8], sl[8];
    bool val[2];
    #pragma unroll
    for (int h = 0; h < 2; ++h) {
        int t = blockIdx.x * 512 + h * 256 + tid;
        val[h] = (t < NE / 4);
        if (val[h]) {
            r4[h] = ((const int4*)rowv)[t];
            c4[h] = ((const int4*)colv)[t];
            bk[4*h+0] = c4[h].x >> BSHIFT; sl[4*h+0] = atomicAdd(&hist[bk[4*h+0]], 1);
            bk[4*h+1] = c4[h].y >> BSHIFT; sl[4*h+1] = atomicAdd(&hist[bk[4*h+1]], 1);
            bk[4*h+2] = c4[h].z >> BSHIFT; sl[4*h+2] = atomicAdd(&hist[bk[4*h+2]], 1);
            bk[4*h+3] = c4[h].w >> BSHIFT; sl[4*h+3] = atomicAdd(&hist[bk[4*h+3]], 1);
        }
    }
    __syncthreads();
    int xcd = blockIdx.x & 7;
    for (int i = tid; i < NBUCK; i += 256)
        bases[i] = hist[i] ? atomicAdd(&gcnt[i * 8 + xcd], hist[i]) : 0;
    __syncthreads();
    #pragma unroll
    for (int h = 0; h < 2; ++h) {
        if (val[h]) {
            #pragma unroll
            for (int e = 0; e < 4; ++e) {
                int c = (e == 0) ? c4[h].x : (e == 1) ? c4[h].y : (e == 2) ? c4[h].z : c4[h].w;
                int r = (e == 0) ? r4[h].x : (e == 1) ? r4[h].y : (e == 2) ? r4[h].z : r4[h].w;
                int p = bases[bk[4*h+e]] + sl[4*h+e];
                if (p < SUBCAP) ebuf[(bk[4*h+e] * 8 + xcd) * SUBCAP + p] = make_int2(c, r);
            }
        }
    }
}

// ---------------- hetero: bucket sort (LDS cursors) + gemm1 ----------------
// Sort blocks (first NBUCK): block k owns nodes [k*256, k*256+256) exclusively;
// LDS per-node cursors; writes degrees AND dinvf = rsqrt(deg+1). Zero global atomics.
// gemm1 blocks: xs[n][c] = bf16( sum_k obs[n][k]*W1[c][k] ) UNSCALED (dinv on
// gather). W1 converted fp32->bf16 during LDS staging. wave = 16 rows x 64 cols;
// A direct from global; W1 LDS XOR-swizzled (byte ^= (row&7)<<4).
__global__ __launch_bounds__(256) void k_sort_gemm1(
        const float* __restrict__ obs, const float* __restrict__ W1,
        unsigned short* __restrict__ xs,
        const int* __restrict__ gcnt, const int2* __restrict__ ebuf,
        int* __restrict__ cursor, float* __restrict__ dinvf,
        int* __restrict__ csr_src) {
    __shared__ char smem[64 * IND * 2];         // gemm: 16KB W1 tile; sort: cursors
    int tid = threadIdx.x;
    if (blockIdx.x < NBUCK) {
        int k = blockIdx.x;
        int lo = k << BSHIFT;
        int* cnt = (int*)smem;
        cnt[tid] = 0;
        __syncthreads();
        for (int x = 0; x < 8; ++x) {
            int len = gcnt[k * 8 + x]; if (len > SUBCAP) len = SUBCAP;
            const int2* run = ebuf + (size_t)(k * 8 + x) * SUBCAP;
            for (int i = tid; i < len; i += 256) {
                int2 e = run[i];
                int s = atomicAdd(&cnt[e.x - lo], 1);       // LDS atomic
                if (s < KMAX) csr_src[e.x * KMAX + s] = e.y;
            }
        }
        __syncthreads();
        int n = lo + tid;
        if (n < NN) {
            cursor[n] = cnt[tid];
            dinvf[n] = rsqrtf((float)(cnt[tid] + 1));
        }
        return;
    }
    char* sB = smem;
    int base = (blockIdx.x - NBUCK) * 64;

    {   // stage W1 fp32 -> bf16 swizzled (64 rows x 32 float4)
        const float4* Wsrc = (const float4*)W1;
        for (int idx = tid; idx < 64 * 32; idx += 256) {
            int row = idx >> 5, c4i = idx & 31;
            float4 w = Wsrc[idx];
            uint2 p;
            p.x = f2bf(w.x) | (f2bf(w.y) << 16);
            p.y = f2bf(w.z) | (f2bf(w.w) << 16);
            int byte = row * (IND * 2) + c4i * 8;
            byte ^= (row & 7) << 4;
            *(uint2*)(sB + byte) = p;
        }
    }
    __syncthreads();

    int wave = tid >> 6, lane = tid & 63;
    int r16 = lane & 15, kg = lane >> 4;
    int arow = base + 16 * wave + r16;
    if (arow >= NN) arow = NN - 1;
    const float4* Ap = (const float4*)(obs + (size_t)arow * IND) + kg * 2;

    float4 va[8];
    #pragma unroll
    for (int s = 0; s < 4; ++s) {
        va[2 * s]     = Ap[s * 8];
        va[2 * s + 1] = Ap[s * 8 + 1];
    }

    f32x4 acc[4];
    #pragma unroll
    for (int j = 0; j < 4; ++j) acc[j] = (f32x4){0.f, 0.f, 0.f, 0.f};

    #pragma unroll
    for (int s = 0; s < 4; ++s) {
        float4 v0 = va[2 * s], v1 = va[2 * s + 1];
        s16x8 a;
        a[0] = (short)f2bf(v0.x); a[1] = (short)f2bf(v0.y);
        a[2] = (short)f2bf(v0.z); a[3] = (short)f2bf(v0.w);
        a[4] = (short)f2bf(v1.x); a[5] = (short)f2bf(v1.y);
        a[6] = (short)f2bf(v1.z); a[7] = (short)f2bf(v1.w);
        int kb = (s * 32 + kg * 8) * 2;
        #pragma unroll
        for (int j = 0; j < 4; ++j) {
            int row = 16 * j + r16;
            int byte = row * (IND * 2) + kb;
            byte ^= (row & 7) << 4;
            s16x8 b = *(const s16x8*)(sB + byte);
            acc[j] = __builtin_amdgcn_mfma_f32_16x16x32_bf16(a, b, acc[j], 0, 0, 0);
        }
    }

    #pragma unroll
    for (int r = 0; r < 4; ++r) {
        int n = base + 16 * wave + kg * 4 + r;
        if (n >= NN) continue;
        #pragma unroll
        for (int j = 0; j < 4; ++j) {
            int c = 16 * j + r16;
            xs[(size_t)n * HID + c] = (unsigned short)f2bf(acc[j][r]);
        }
    }
}

// ---------------- fused agg1 + gemm2 (branch-free batched gathers) ----------------
__global__ __launch_bounds__(256) void k_agg_gemm(
        const unsigned short* __restrict__ xs, const int* __restrict__ cursor,
        const float* __restrict__ dinvf, const int* __restrict__ csr_src,
        const float* __restrict__ bias, const float* __restrict__ W2,
        unsigned short* __restrict__ xs2) {
    __shared__ char smem[2 * 64 * HID * 2];
    char* sA = smem;
    char* sB = smem + 64 * HID * 2;
    int tid = threadIdx.x;
    int base = blockIdx.x * 64;

    {   // stage W2 fp32 -> bf16 swizzled (64 rows x 16 float4)
        const float4* Wsrc = (const float4*)W2;
        for (int idx = tid; idx < 64 * 16; idx += 256) {
            int row = idx >> 4, c4i = idx & 15;
            float4 w = Wsrc[idx];
            uint2 p;
            p.x = f2bf(w.x) | (f2bf(w.y) << 16);
            p.y = f2bf(w.z) | (f2bf(w.w) << 16);
            int byte = row * (HID * 2) + c4i * 8;
            byte ^= (row & 7) << 4;
            *(uint2*)(sB + byte) = p;
        }
    }

    int lane = tid & 63;
    int l16 = lane & 15, gbase = lane & 48;
    int grp = tid >> 4;
    const uint2* src = (const uint2*)xs;
    float4 bb = ((const float4*)bias)[l16];

    int degA[4], cntA[4], idxA[4];
    uint2 svA[4];
    float drA[4];
    #pragma unroll
    for (int s4 = 0; s4 < 4; ++s4) {
        int node = base + s4 * 16 + grp;
        bool ok = node < NN;
        int nc = ok ? node : NN - 1;
        int deg = cursor[nc];
        degA[s4] = deg;
        cntA[s4] = ok ? (deg < KMAX ? deg : KMAX) : 0;
        idxA[s4] = csr_src[nc * KMAX + l16];    // 64B/group: slots 0..15
        svA[s4]  = src[(size_t)nc * 16 + l16];  // self row
    }
    #pragma unroll
    for (int s4 = 0; s4 < 4; ++s4) {
        drA[s4] = (l16 < cntA[s4]) ? dinvf[idxA[s4]] : 0.0f;
    }

    #pragma unroll
    for (int s4 = 0; s4 < 4; ++s4) {
        int row = s4 * 16 + grp;
        int node = base + row;
        int cnt = cntA[s4];
        float dn = rsqrtf((float)(degA[s4] + 1));
        uint2 sv = svA[s4];
        float a0 = __uint_as_float(sv.x << 16) * dn;
        float a1 = __uint_as_float(sv.x & 0xFFFF0000u) * dn;
        float a2 = __uint_as_float(sv.y << 16) * dn;
        float a3 = __uint_as_float(sv.y & 0xFFFF0000u) * dn;
        uint2 v[8];
        #pragma unroll
        for (int j = 0; j < 8; ++j) {
            int r = __shfl(idxA[s4], gbase + j, 64);
            r = (j < cnt) ? r : 0;
            v[j] = src[(size_t)r * 16 + l16];
        }
        #pragma unroll
        for (int j = 0; j < 8; ++j) {
            float dr = __shfl(drA[s4], gbase + j, 64);  // 0 for invalid slots
            ACC4(v[j], dr)
        }
        if (cnt > 8) {
            int c16 = cnt < 16 ? cnt : 16;
            for (int j = 8; j < c16; ++j) {
                int r    = __shfl(idxA[s4], gbase + j, 64);
                float dr = __shfl(drA[s4], gbase + j, 64);
                uint2 vv = src[(size_t)r * 16 + l16];
                ACC4(vv, dr)
            }
            for (int j = 16; j < cnt; ++j) {    // ultra-rare
                int r = csr_src[node * KMAX + j];
                float dr = dinvf[r];
                uint2 vv = src[(size_t)r * 16 + l16];
                ACC4(vv, dr)
            }
        }
        float h0 = fmaxf(fmaf(dn, a0, bb.x), 0.f);
        float h1 = fmaxf(fmaf(dn, a1, bb.y), 0.f);
        float h2 = fmaxf(fmaf(dn, a2, bb.z), 0.f);
        float h3 = fmaxf(fmaf(dn, a3, bb.w), 0.f);
        uint2 o;
        o.x = f2bf(h0) | (f2bf(h1) << 16);
        o.y = f2bf(h2) | (f2bf(h3) << 16);
        if (node >= NN) { o.x = 0u; o.y = 0u; }
        int byte = row * (HID * 2) + l16 * 8;
        byte ^= (row & 7) << 4;
        *(uint2*)(sA + byte) = o;
    }
    __syncthreads();

    int wave = tid >> 6;
    int wr = wave >> 1, wc = wave & 1;
    int r16 = lane & 15, kg = lane >> 4;

    f32x4 acc[2][2];
    #pragma unroll
    for (int i = 0; i < 2; ++i)
        #pragma unroll
        for (int j = 0; j < 2; ++j)
            acc[i][j] = (f32x4){0.f, 0.f, 0.f, 0.f};

    #pragma unroll
    for (int s = 0; s < HID / 32; ++s) {
        int kb = (s * 32 + kg * 8) * 2;
        s16x8 a[2], b[2];
        #pragma unroll
        for (int i = 0; i < 2; ++i) {
            int row = 32 * wr + 16 * i + r16;
            int byte = row * (HID * 2) + kb;
            byte ^= (row & 7) << 4;
            a[i] = *(const s16x8*)(sA + byte);
        }
        #pragma unroll
        for (int j = 0; j < 2; ++j) {
            int row = 32 * wc + 16 * j + r16;
            int byte = row * (HID * 2) + kb;
            byte ^= (row & 7) << 4;
            b[j] = *(const s16x8*)(sB + byte);
        }
        #pragma unroll
        for (int i = 0; i < 2; ++i)
            #pragma unroll
            for (int j = 0; j < 2; ++j)
                acc[i][j] = __builtin_amdgcn_mfma_f32_16x16x32_bf16(a[i], b[j], acc[i][j], 0, 0, 0);
    }

    #pragma unroll
    for (int i = 0; i < 2; ++i) {
        #pragma unroll
        for (int r = 0; r < 4; ++r) {
            int n = base + 32 * wr + 16 * i + kg * 4 + r;
            if (n >= NN) continue;
            float d = dinvf[n];                 // pre-scale layer-2 source side
            #pragma unroll
            for (int j = 0; j < 2; ++j) {
                int c = 32 * wc + 16 * j + r16;
                xs2[(size_t)n * HID + c] = (unsigned short)f2bf(acc[i][j][r] * d);
            }
        }
    }
}

// ---------------- agg2 + final dot (needed nodes only; batched gathers) ----------------
__global__ __launch_bounds__(256) void k_agg_out(const unsigned short* __restrict__ xs,
                      const int* __restrict__ cursor, const int* __restrict__ csr_src,
                      const float* __restrict__ bias, const float* __restrict__ W3,
                      const float* __restrict__ b3, float* __restrict__ outp) {
    int tid = threadIdx.x;
    int lane = tid & 63;
    int l16 = lane & 15, gbase = lane & 48;
    int q = blockIdx.x * 16 + (tid >> 4);
    if (q >= NOUT) return;
    int g15 = q / 12, jj12 = q - g15 * 12;
    int node = g15 * 15 + 3 + jj12;
    int deg = cursor[node];
    int cnt = deg < KMAX ? deg : KMAX;
    float dn = rsqrtf((float)(deg + 1));
    const uint2* src = (const uint2*)xs;
    int idx0 = csr_src[node * KMAX + l16];      // 64B: slots 0..15
    float w0 = (l16 < cnt) ? 1.0f : 0.0f;       // slot validity weight
    uint2 sv = src[(size_t)node * 16 + l16];
    float a0 = __uint_as_float(sv.x << 16);
    float a1 = __uint_as_float(sv.x & 0xFFFF0000u);
    float a2 = __uint_as_float(sv.y << 16);
    float a3 = __uint_as_float(sv.y & 0xFFFF0000u);
    uint2 v[8];
    #pragma unroll
    for (int j = 0; j < 8; ++j) {
        int r = __shfl(idx0, gbase + j, 64);
        r = (j < cnt) ? r : 0;
        v[j] = src[(size_t)r * 16 + l16];
    }
    #pragma unroll
    for (int j = 0; j < 8; ++j) {
        float w = __shfl(w0, gbase + j, 64);
        ACC4(v[j], w)
    }
    if (cnt > 8) {
        int c16 = cnt < 16 ? cnt : 16;
        for (int j = 8; j < c16; ++j) {
            int r = __shfl(idx0, gbase + j, 64);
            uint2 vv = src[(size_t)r * 16 + l16];
            ACC4(vv, 1.0f)
        }
        for (int j = 16; j < cnt; ++j) {
            int r = csr_src[node * KMAX + j];
            uint2 vv = src[(size_t)r * 16 + l16];
            ACC4(vv, 1.0f)
        }
    }
    float4 bb = ((const float4*)bias)[l16];
    float h0 = fmaxf(fmaf(dn, a0, bb.x), 0.f);
    float h1 = fmaxf(fmaf(dn, a1, bb.y), 0.f);
    float h2 = fmaxf(fmaf(dn, a2, bb.z), 0.f);
    float h3 = fmaxf(fmaf(dn, a3, bb.w), 0.f);
    float4 ww = ((const float4*)W3)[l16];
    float v3 = h0 * ww.x + h1 * ww.y + h2 * ww.z + h3 * ww.w;
    v3 += __shfl_xor(v3, 1, 64);
    v3 += __shfl_xor(v3, 2, 64);
    v3 += __shfl_xor(v3, 4, 64);
    v3 += __shfl_xor(v3, 8, 64);                // reduce within the 16-lane group
    if (l16 == 0) outp[q] = v3 + b3[0];
}

extern "C" void kernel_launch(void* const* d_in, const int* in_sizes, int n_in,
                              void* d_out, int out_size, void* d_ws, size_t ws_size,
                              hipStream_t stream) {
    const float* obs = (const float*)d_in[0];
    const int*   ei  = (const int*)d_in[1];
    const float* W1  = (const float*)d_in[2];
    const float* b1  = (const float*)d_in[3];
    const float* W2  = (const float*)d_in[4];
    const float* b2  = (const float*)d_in[5];
    const float* W3  = (const float*)d_in[6];
    const float* b3  = (const float*)d_in[7];
    float* out = (float*)d_out;

    char* ws = (char*)d_ws;
    size_t off = 0;
    auto alloc = [&](size_t bytes) -> void* {
        void* p = ws + off;
        off += (bytes + 255) & ~(size_t)255;
        return p;
    };
    int*   gcnt    = (int*)  alloc((size_t)NBUCK * 8 * 4);          // 18.8 KB
    int*   cursor  = (int*)  alloc((size_t)NN * 4);
    float* dinvf   = (float*)alloc((size_t)NN * 4);
    int*   csr_src = (int*)  alloc((size_t)NN * KMAX * 4);          // 19.2 MB
    int2*  ebuf    = (int2*) alloc((size_t)NBUCK * 8 * SUBCAP * 8); // 8.4 MB
    unsigned short* XB  = (unsigned short*)alloc((size_t)NN * HID * 2);
    unsigned short* XB2 = (unsigned short*)alloc((size_t)NN * HID * 2);

    const int* rowv = ei;
    const int* colv = ei + NE;

    k_zero<<<(NBUCK * 8 + 255) / 256, 256, 0, stream>>>(gcnt);
    k_part<<<PARTB, 256, 0, stream>>>(rowv, colv, gcnt, ebuf);
    k_sort_gemm1<<<NBUCK + GEMM_GRID, 256, 0, stream>>>(obs, W1, XB, gcnt, ebuf,
                                                        cursor, dinvf, csr_src);
    k_agg_gemm<<<GEMM_GRID, 256, 0, stream>>>(XB, cursor, dinvf, csr_src, b1, W2, XB2);
    k_agg_out<<<(NOUT + 15) / 16, 256, 0, stream>>>(XB2, cursor, csr_src, b2, W3, b3, out);
}